// Round 6
// baseline (1247.030 us; speedup 1.0000x reference)
//
#include <hip/hip_runtime.h>
#include <stdint.h>

// x[N,128] f32, edge_index[2,E] int32/64, ew[E] f32, W1[64,128], b1[64], W2[128,64], b2[128]
#define FIN 128
#define FHID 64
#define CHUNK 2048
#define FIX_SCALE 65536.0f      // 2^16 fixed point for weighted degree
#define FIX_INV   (1.0f / 65536.0f)

// ---------- dtype detection: int64 edge_index has odd 32-bit words == 0 ----------
__global__ void k_detect(const uint32_t* __restrict__ ei, int* __restrict__ flag) {
    if (blockIdx.x == 0 && threadIdx.x == 0) {
        uint32_t o = 0;
        #pragma unroll
        for (int i = 1; i < 16; i += 2) o |= ei[i];
        *flag = (o == 0) ? 1 : 0;
    }
}

__device__ __forceinline__ int edge_at(const void* ei, long long idx, int is64) {
    if (is64) return (int)((const long long*)ei)[idx];
    return ((const int*)ei)[idx];
}

// ---------- packed degree + per-edge rank: one u32 atomic per edge ----------
// bits [24:31] = count (max deg ~70 << 255), bits [0:23] = wdeg in 2^-16 fixed
// point (max 70*65536 ~ 4.6M < 2^24). Quantization rel err ~1e-5 on wdeg.
__global__ __launch_bounds__(256) void k_deg(const void* __restrict__ ei, const float* __restrict__ w,
                                             unsigned int* __restrict__ packed,
                                             unsigned char* __restrict__ rank,
                                             const int* __restrict__ flag, int E) {
    int e = blockIdx.x * 256 + threadIdx.x;
    if (e >= E) return;
    int is64 = *flag;
    int c = edge_at(ei, (long long)E + e, is64);
    unsigned int inc = (1u << 24) | __float2uint_rn(w[e] * FIX_SCALE);
    unsigned int old = atomicAdd(&packed[c], inc);
    rank[e] = (unsigned char)(old >> 24);
}

// ---------- packed -> deg^-1/2 ----------
__global__ __launch_bounds__(256) void k_dis(const unsigned int* __restrict__ packed,
                                             float* __restrict__ dis, int N) {
    int i = blockIdx.x * 256 + threadIdx.x;
    if (i < N) {
        float d = (float)(packed[i] & 0xFFFFFFu) * FIX_INV;
        dis[i] = (d > 0.f) ? rsqrtf(d) : 0.f;
    }
}

// ---------- exclusive scan of packed counts -> row_start ----------
__global__ __launch_bounds__(256) void k_scan_part(const unsigned int* __restrict__ packed,
                                                   int* __restrict__ partial, int N) {
    __shared__ int sdata[256];
    int b = blockIdx.x, t = threadIdx.x;
    int base = b * CHUNK;
    int sum = 0;
    #pragma unroll
    for (int q = 0; q < CHUNK / 256; ++q) {
        int idx = base + q * 256 + t;
        if (idx < N) sum += (int)(packed[idx] >> 24);
    }
    sdata[t] = sum; __syncthreads();
    for (int off = 128; off > 0; off >>= 1) {
        if (t < off) sdata[t] += sdata[t + off];
        __syncthreads();
    }
    if (t == 0) partial[b] = sdata[0];
}

__global__ void k_scan_top(int* partial, int nparts, int* row_start, int N) {
    if (blockIdx.x == 0 && threadIdx.x == 0) {
        int run = 0;
        for (int i = 0; i < nparts; ++i) { int v = partial[i]; partial[i] = run; run += v; }
        row_start[N] = run;   // == E
    }
}

__global__ __launch_bounds__(256) void k_scan_chunk(const unsigned int* __restrict__ packed,
                                                    const int* __restrict__ partial,
                                                    int* __restrict__ row_start, int N) {
    __shared__ int tsum[256];
    __shared__ int toff[256];
    int b = blockIdx.x, t = threadIdx.x;
    int base = b * CHUNK + t * 8;
    int v[8]; int s = 0;
    #pragma unroll
    for (int q = 0; q < 8; ++q) {
        int idx = base + q;
        v[q] = (idx < N) ? (int)(packed[idx] >> 24) : 0;
        s += v[q];
    }
    tsum[t] = s; __syncthreads();
    if (t == 0) {
        int run = partial[b];
        for (int i = 0; i < 256; ++i) { int x = tsum[i]; toff[i] = run; run += x; }
    }
    __syncthreads();
    int ex = toff[t];
    #pragma unroll
    for (int q = 0; q < 8; ++q) {
        int idx = base + q;
        if (idx < N) row_start[idx] = ex;
        ex += v[q];
    }
}

// ---------- CSR fill (atomic-free): csr[row_start[c]+rank[e]] = {src, norm} ----------
__global__ __launch_bounds__(256) void k_fill(const void* __restrict__ ei, const float* __restrict__ w,
                                              const float* __restrict__ dis,
                                              const int* __restrict__ row_start,
                                              const unsigned char* __restrict__ rank,
                                              int2* __restrict__ csr,
                                              const int* __restrict__ flag, int E) {
    int e = blockIdx.x * 256 + threadIdx.x;
    if (e >= E) return;
    int is64 = *flag;
    int r = edge_at(ei, e, is64);
    int c = edge_at(ei, (long long)E + e, is64);
    float nm = dis[r] * w[e] * dis[c];
    int pos = row_start[c] + (int)rank[e];
    csr[pos] = make_int2(r, __float_as_int(nm));
}

// ---------- W2 pack: W2p[k*64+lane] = {W2[lane][k], W2[lane+64][k]} ----------
__global__ __launch_bounds__(256) void k_w2p(const float* __restrict__ W2, float2* __restrict__ W2p) {
    int i = blockIdx.x * 256 + threadIdx.x;   // 4096 elements
    if (i < FHID * FHID) {
        int k = i >> 6, lane = i & 63;
        W2p[(size_t)k * 64 + lane] =
            make_float2(W2[(size_t)lane * FHID + k], W2[(size_t)(lane + 64) * FHID + k]);
    }
}

// ---------- GEMM1: h1lin[N,64] = x[N,128] @ W1[64,128]^T ----------
__global__ __launch_bounds__(256, 4) void k_gemm1(const float* __restrict__ x, const float* __restrict__ W1,
                                                  float* __restrict__ h1lin, int N) {
    __shared__ float Wt[FIN * 65];      // Wt[k*65+j] = W1[j*128+k], padded: conflict-free
    __shared__ float xt[32 * FIN];      // 16 KB
    int t = threadIdx.x;
    for (int i = t; i < FHID * FIN; i += 256) {
        int j = i >> 7, k = i & 127;
        Wt[k * 65 + j] = W1[i];         // lane-varying k -> stride 65 -> conflict-free
    }
    int r0 = blockIdx.x * 32;
    const float4* xg = (const float4*)(x + (size_t)r0 * FIN);
    float4* xt4 = (float4*)xt;
    #pragma unroll
    for (int q = 0; q < 4; ++q) {
        int i = t + q * 256;            // 1024 float4 total, 32 per row
        if (r0 + (i >> 5) < N) xt4[i] = xg[i];
    }
    __syncthreads();
    int j = t & 63, rg = t >> 6;        // rg uniform per wave
    float acc[8];
    #pragma unroll
    for (int r = 0; r < 8; ++r) acc[r] = 0.f;
    for (int kk = 0; kk < FIN; kk += 4) {
        float w0 = Wt[(kk + 0) * 65 + j];
        float w1 = Wt[(kk + 1) * 65 + j];
        float w2 = Wt[(kk + 2) * 65 + j];
        float w3 = Wt[(kk + 3) * 65 + j];
        #pragma unroll
        for (int r = 0; r < 8; ++r) {
            float4 xv = xt4[(rg * 8 + r) * 32 + (kk >> 2)];
            acc[r] += xv.x * w0 + xv.y * w1 + xv.z * w2 + xv.w * w3;
        }
    }
    #pragma unroll
    for (int r = 0; r < 8; ++r) {
        int row = r0 + rg * 8 + r;
        if (row < N) h1lin[(size_t)row * FHID + j] = acc[r];
    }
}

// ---------- gather-accumulate one node's row: 8 independent chains ----------
__device__ __forceinline__ float agg_row(const int2* __restrict__ csr, int s, int epos,
                                         const float* __restrict__ tab, int lane) {
    float a0 = 0.f, a1 = 0.f, a2 = 0.f, a3 = 0.f, a4 = 0.f, a5 = 0.f, a6 = 0.f, a7 = 0.f;
    for (int base = s; base < epos; base += 64) {
        int m = epos - base; if (m > 64) m = 64;
        int2 ent = (lane < m) ? csr[base + lane] : make_int2(0, 0);
        int i = 0;
        for (; i + 8 <= m; i += 8) {
            int   s0 = __shfl(ent.x, i + 0); float n0 = __shfl(__int_as_float(ent.y), i + 0);
            int   s1 = __shfl(ent.x, i + 1); float n1 = __shfl(__int_as_float(ent.y), i + 1);
            int   s2 = __shfl(ent.x, i + 2); float n2 = __shfl(__int_as_float(ent.y), i + 2);
            int   s3 = __shfl(ent.x, i + 3); float n3 = __shfl(__int_as_float(ent.y), i + 3);
            int   s4 = __shfl(ent.x, i + 4); float n4 = __shfl(__int_as_float(ent.y), i + 4);
            int   s5 = __shfl(ent.x, i + 5); float n5 = __shfl(__int_as_float(ent.y), i + 5);
            int   s6 = __shfl(ent.x, i + 6); float n6 = __shfl(__int_as_float(ent.y), i + 6);
            int   s7 = __shfl(ent.x, i + 7); float n7 = __shfl(__int_as_float(ent.y), i + 7);
            float v0 = tab[((size_t)(unsigned)s0 << 6) + lane];
            float v1 = tab[((size_t)(unsigned)s1 << 6) + lane];
            float v2 = tab[((size_t)(unsigned)s2 << 6) + lane];
            float v3 = tab[((size_t)(unsigned)s3 << 6) + lane];
            float v4 = tab[((size_t)(unsigned)s4 << 6) + lane];
            float v5 = tab[((size_t)(unsigned)s5 << 6) + lane];
            float v6 = tab[((size_t)(unsigned)s6 << 6) + lane];
            float v7 = tab[((size_t)(unsigned)s7 << 6) + lane];
            a0 += n0 * v0; a1 += n1 * v1; a2 += n2 * v2; a3 += n3 * v3;
            a4 += n4 * v4; a5 += n5 * v5; a6 += n6 * v6; a7 += n7 * v7;
        }
        for (; i < m; ++i) {
            int   s0 = __shfl(ent.x, i); float n0 = __shfl(__int_as_float(ent.y), i);
            a0 += n0 * tab[((size_t)(unsigned)s0 << 6) + lane];
        }
    }
    return ((a0 + a1) + (a2 + a3)) + ((a4 + a5) + (a6 + a7));
}

// ---------- aggregation layer1: h1 = relu(sum norm*h1lin[src] + b1), F=64 ----------
__global__ __launch_bounds__(256) void k_agg1(const int2* __restrict__ csr, const int* __restrict__ row_start,
                                              const float* __restrict__ h1lin, const float* __restrict__ b1,
                                              float* __restrict__ h1, int N) {
    int wid = threadIdx.x >> 6, lane = threadIdx.x & 63;
    int node = blockIdx.x * 4 + wid;
    if (node >= N) return;
    float acc = agg_row(csr, row_start[node], row_start[node + 1], h1lin, lane);
    h1[(size_t)node * FHID + lane] = fmaxf(acc + b1[lane], 0.f);
}

// ---------- fused agg2 + GEMM2 (no LDS): out = relu((sum norm*h1[src]) @ W2^T + b2) ----------
__global__ __launch_bounds__(256) void k_agg2f(const int2* __restrict__ csr, const int* __restrict__ row_start,
                                               const float* __restrict__ h1, const float2* __restrict__ W2p,
                                               const float* __restrict__ b2, float* __restrict__ out, int N) {
    int wid = threadIdx.x >> 6, lane = threadIdx.x & 63;
    int node = blockIdx.x * 4 + wid;
    if (node >= N) return;
    float acc = agg_row(csr, row_start[node], row_start[node + 1], h1, lane);
    // epilogue: out[node][j] = relu(sum_k acc_k * W2[j][k] + b2[j]), j = lane, lane+64
    float o0 = b2[lane], o1 = b2[lane + 64];
    #pragma unroll 4
    for (int k = 0; k < FHID; ++k) {
        float a = __shfl(acc, k);       // uniform index -> broadcast
        float2 wv = W2p[(size_t)k * 64 + lane];   // coalesced 512B, L1-resident
        o0 += a * wv.x;
        o1 += a * wv.y;
    }
    out[(size_t)node * FIN + lane] = fmaxf(o0, 0.f);
    out[(size_t)node * FIN + 64 + lane] = fmaxf(o1, 0.f);
}

extern "C" void kernel_launch(void* const* d_in, const int* in_sizes, int n_in,
                              void* d_out, int out_size, void* d_ws, size_t ws_size,
                              hipStream_t stream) {
    const float* x  = (const float*)d_in[0];
    const void*  ei = d_in[1];
    const float* w  = (const float*)d_in[2];
    const float* W1 = (const float*)d_in[3];
    const float* b1 = (const float*)d_in[4];
    const float* W2 = (const float*)d_in[5];
    const float* b2 = (const float*)d_in[6];
    float* out = (float*)d_out;
    int N = in_sizes[0] / FIN;
    int E = in_sizes[2];

    char* ws = (char*)d_ws;
    size_t off = 0;
    auto alloc = [&](size_t b) { size_t o = off; off = (off + b + 255) & ~255ULL; return o; };
    int*   flag      = (int*)(ws + alloc(4));
    unsigned int* packed = (unsigned int*)(ws + alloc((size_t)N * 4));
    float* dis       = (float*)(ws + alloc((size_t)N * 4));
    int*   row_start = (int*)(ws + alloc((size_t)(N + 1) * 4));
    int*   partial   = (int*)(ws + alloc(4096));
    float2* W2p      = (float2*)(ws + alloc((size_t)FHID * FHID * 8));
    int2*  csr       = (int2*)(ws + alloc((size_t)E * 8));
    float* h1        = (float*)(ws + alloc((size_t)N * FHID * 4));
    float* h1lin     = (float*)(ws + alloc((size_t)N * FHID * 4));
    unsigned char* rank = (unsigned char*)h1lin;  // alias: rank (E bytes <= N*256B) dead before k_gemm1 writes h1lin

    hipMemsetAsync(packed, 0, (size_t)N * 4, stream);

    k_detect<<<1, 64, 0, stream>>>((const uint32_t*)ei, flag);

    int eb = (E + 255) / 256;
    k_deg<<<eb, 256, 0, stream>>>(ei, w, packed, rank, flag, E);
    k_dis<<<(N + 255) / 256, 256, 0, stream>>>(packed, dis, N);

    int nparts = (N + CHUNK - 1) / CHUNK;
    k_scan_part<<<nparts, 256, 0, stream>>>(packed, partial, N);
    k_scan_top<<<1, 64, 0, stream>>>(partial, nparts, row_start, N);
    k_scan_chunk<<<nparts, 256, 0, stream>>>(packed, partial, row_start, N);

    k_fill<<<eb, 256, 0, stream>>>(ei, w, dis, row_start, rank, csr, flag, E);
    k_w2p<<<(FHID * FHID + 255) / 256, 256, 0, stream>>>(W2, W2p);

    k_gemm1<<<(N + 31) / 32, 256, 0, stream>>>(x, W1, h1lin, N);
    k_agg1<<<(N + 3) / 4, 256, 0, stream>>>(csr, row_start, h1lin, b1, h1, N);
    k_agg2f<<<(N + 3) / 4, 256, 0, stream>>>(csr, row_start, h1, W2p, b2, out, N);
}

// Round 7
// 1185.053 us; speedup vs baseline: 1.0523x; 1.0523x over previous
//
#include <hip/hip_runtime.h>
#include <stdint.h>

// x[N,128] f32, edge_index[2,E] int32/64, ew[E] f32, W1[64,128], b1[64], W2[128,64], b2[128]
#define FIN 128
#define FHID 64
#define CHUNK 2048
#define FIX_SCALE 65536.0f      // 2^16 fixed point for weighted degree
#define FIX_INV   (1.0f / 65536.0f)

__device__ __forceinline__ float bf2f(unsigned short u) {
    union { unsigned int i; float f; } v; v.i = ((unsigned int)u) << 16; return v.f;
}
__device__ __forceinline__ unsigned short f2bf(float f) {
    union { float f; unsigned int i; } v; v.f = f;
    unsigned int u = v.i;
    u += 0x7FFFu + ((u >> 16) & 1u);   // round-to-nearest-even
    return (unsigned short)(u >> 16);
}

// ---------- dtype detection: int64 edge_index has odd 32-bit words == 0 ----------
__global__ void k_detect(const uint32_t* __restrict__ ei, int* __restrict__ flag) {
    if (blockIdx.x == 0 && threadIdx.x == 0) {
        uint32_t o = 0;
        #pragma unroll
        for (int i = 1; i < 16; i += 2) o |= ei[i];
        *flag = (o == 0) ? 1 : 0;
    }
}

__device__ __forceinline__ int edge_at(const void* ei, long long idx, int is64) {
    if (is64) return (int)((const long long*)ei)[idx];
    return ((const int*)ei)[idx];
}

// ---------- packed degree + per-edge rank: one u32 atomic per edge ----------
// bits [24:31] = count (max deg ~70 << 255), bits [0:23] = wdeg in 2^-16 fixed
// point (max ~70*65536 ~ 4.6M < 2^24). Quantization rel err ~1e-5 on wdeg.
__global__ __launch_bounds__(256) void k_deg(const void* __restrict__ ei, const float* __restrict__ w,
                                             unsigned int* __restrict__ packed,
                                             unsigned char* __restrict__ rank,
                                             const int* __restrict__ flag, int E) {
    int e = blockIdx.x * 256 + threadIdx.x;
    if (e >= E) return;
    int is64 = *flag;
    int c = edge_at(ei, (long long)E + e, is64);
    unsigned int inc = (1u << 24) | __float2uint_rn(w[e] * FIX_SCALE);
    unsigned int old = atomicAdd(&packed[c], inc);
    rank[e] = (unsigned char)(old >> 24);
}

// ---------- packed -> deg^-1/2 ----------
__global__ __launch_bounds__(256) void k_dis(const unsigned int* __restrict__ packed,
                                             float* __restrict__ dis, int N) {
    int i = blockIdx.x * 256 + threadIdx.x;
    if (i < N) {
        float d = (float)(packed[i] & 0xFFFFFFu) * FIX_INV;
        dis[i] = (d > 0.f) ? rsqrtf(d) : 0.f;
    }
}

// ---------- exclusive scan of packed counts -> row_start ----------
__global__ __launch_bounds__(256) void k_scan_part(const unsigned int* __restrict__ packed,
                                                   int* __restrict__ partial, int N) {
    __shared__ int sdata[256];
    int b = blockIdx.x, t = threadIdx.x;
    int base = b * CHUNK;
    int sum = 0;
    #pragma unroll
    for (int q = 0; q < CHUNK / 256; ++q) {
        int idx = base + q * 256 + t;
        if (idx < N) sum += (int)(packed[idx] >> 24);
    }
    sdata[t] = sum; __syncthreads();
    for (int off = 128; off > 0; off >>= 1) {
        if (t < off) sdata[t] += sdata[t + off];
        __syncthreads();
    }
    if (t == 0) partial[b] = sdata[0];
}

__global__ void k_scan_top(int* partial, int nparts, int* row_start, int N) {
    if (blockIdx.x == 0 && threadIdx.x == 0) {
        int run = 0;
        for (int i = 0; i < nparts; ++i) { int v = partial[i]; partial[i] = run; run += v; }
        row_start[N] = run;   // == E
    }
}

__global__ __launch_bounds__(256) void k_scan_chunk(const unsigned int* __restrict__ packed,
                                                    const int* __restrict__ partial,
                                                    int* __restrict__ row_start, int N) {
    __shared__ int tsum[256];
    __shared__ int toff[256];
    int b = blockIdx.x, t = threadIdx.x;
    int base = b * CHUNK + t * 8;
    int v[8]; int s = 0;
    #pragma unroll
    for (int q = 0; q < 8; ++q) {
        int idx = base + q;
        v[q] = (idx < N) ? (int)(packed[idx] >> 24) : 0;
        s += v[q];
    }
    tsum[t] = s; __syncthreads();
    if (t == 0) {
        int run = partial[b];
        for (int i = 0; i < 256; ++i) { int x = tsum[i]; toff[i] = run; run += x; }
    }
    __syncthreads();
    int ex = toff[t];
    #pragma unroll
    for (int q = 0; q < 8; ++q) {
        int idx = base + q;
        if (idx < N) row_start[idx] = ex;
        ex += v[q];
    }
}

// ---------- CSR fill (atomic-free): csr[row_start[c]+rank[e]] = {src, norm} ----------
__global__ __launch_bounds__(256) void k_fill(const void* __restrict__ ei, const float* __restrict__ w,
                                              const float* __restrict__ dis,
                                              const int* __restrict__ row_start,
                                              const unsigned char* __restrict__ rank,
                                              int2* __restrict__ csr,
                                              const int* __restrict__ flag, int E) {
    int e = blockIdx.x * 256 + threadIdx.x;
    if (e >= E) return;
    int is64 = *flag;
    int r = edge_at(ei, e, is64);
    int c = edge_at(ei, (long long)E + e, is64);
    float nm = dis[r] * w[e] * dis[c];
    int pos = row_start[c] + (int)rank[e];
    csr[pos] = make_int2(r, __float_as_int(nm));
}

// ---------- W2 pack: W2p[k*64+lane] = {W2[lane][k], W2[lane+64][k]} ----------
__global__ __launch_bounds__(256) void k_w2p(const float* __restrict__ W2, float2* __restrict__ W2p) {
    int i = blockIdx.x * 256 + threadIdx.x;   // 4096 elements
    if (i < FHID * FHID) {
        int k = i >> 6, lane = i & 63;
        W2p[(size_t)k * 64 + lane] =
            make_float2(W2[(size_t)lane * FHID + k], W2[(size_t)(lane + 64) * FHID + k]);
    }
}

// ---------- GEMM1: h1lin[N,64](bf16, deterministic) = x[N,128] @ W1^T ----------
__global__ __launch_bounds__(256, 4) void k_gemm1(const float* __restrict__ x, const float* __restrict__ W1,
                                                  unsigned short* __restrict__ h1lin, int N) {
    __shared__ float Wt[FIN * 65];      // Wt[k*65+j] = W1[j*128+k], padded: conflict-free
    __shared__ float xt[32 * FIN];      // 16 KB
    int t = threadIdx.x;
    for (int i = t; i < FHID * FIN; i += 256) {
        int j = i >> 7, k = i & 127;
        Wt[k * 65 + j] = W1[i];         // lane-varying k -> stride 65 -> conflict-free
    }
    int r0 = blockIdx.x * 32;
    const float4* xg = (const float4*)(x + (size_t)r0 * FIN);
    float4* xt4 = (float4*)xt;
    #pragma unroll
    for (int q = 0; q < 4; ++q) {
        int i = t + q * 256;            // 1024 float4 total, 32 per row
        if (r0 + (i >> 5) < N) xt4[i] = xg[i];
    }
    __syncthreads();
    int j = t & 63, rg = t >> 6;        // rg uniform per wave
    float acc[8];
    #pragma unroll
    for (int r = 0; r < 8; ++r) acc[r] = 0.f;
    for (int kk = 0; kk < FIN; kk += 4) {
        float w0 = Wt[(kk + 0) * 65 + j];
        float w1 = Wt[(kk + 1) * 65 + j];
        float w2 = Wt[(kk + 2) * 65 + j];
        float w3 = Wt[(kk + 3) * 65 + j];
        #pragma unroll
        for (int r = 0; r < 8; ++r) {
            float4 xv = xt4[(rg * 8 + r) * 32 + (kk >> 2)];
            acc[r] += xv.x * w0 + xv.y * w1 + xv.z * w2 + xv.w * w3;
        }
    }
    #pragma unroll
    for (int r = 0; r < 8; ++r) {
        int row = r0 + rg * 8 + r;
        if (row < N) h1lin[(size_t)row * FHID + j] = f2bf(acc[r]);
    }
}

// ---------- gather-accumulate one node's row: 4 independent chains (proven) ----------
// f32 table variant
__device__ __forceinline__ float agg_row_f32(const int2* __restrict__ csr, int s, int epos,
                                             const float* __restrict__ tab, int lane) {
    float a0 = 0.f, a1 = 0.f, a2 = 0.f, a3 = 0.f;
    for (int base = s; base < epos; base += 64) {
        int m = epos - base; if (m > 64) m = 64;
        int2 ent = (lane < m) ? csr[base + lane] : make_int2(0, 0);
        int i = 0;
        for (; i + 4 <= m; i += 4) {
            int   s0 = __shfl(ent.x, i + 0); float n0 = __shfl(__int_as_float(ent.y), i + 0);
            int   s1 = __shfl(ent.x, i + 1); float n1 = __shfl(__int_as_float(ent.y), i + 1);
            int   s2 = __shfl(ent.x, i + 2); float n2 = __shfl(__int_as_float(ent.y), i + 2);
            int   s3 = __shfl(ent.x, i + 3); float n3 = __shfl(__int_as_float(ent.y), i + 3);
            float v0 = tab[((size_t)(unsigned)s0 << 6) + lane];
            float v1 = tab[((size_t)(unsigned)s1 << 6) + lane];
            float v2 = tab[((size_t)(unsigned)s2 << 6) + lane];
            float v3 = tab[((size_t)(unsigned)s3 << 6) + lane];
            a0 += n0 * v0; a1 += n1 * v1; a2 += n2 * v2; a3 += n3 * v3;
        }
        for (; i < m; ++i) {
            int   s0 = __shfl(ent.x, i); float n0 = __shfl(__int_as_float(ent.y), i);
            a0 += n0 * tab[((size_t)(unsigned)s0 << 6) + lane];
        }
    }
    return (a0 + a1) + (a2 + a3);
}

// bf16 table variant (table contents deterministic -> replay-safe)
__device__ __forceinline__ float agg_row_bf16(const int2* __restrict__ csr, int s, int epos,
                                              const unsigned short* __restrict__ tab, int lane) {
    float a0 = 0.f, a1 = 0.f, a2 = 0.f, a3 = 0.f;
    for (int base = s; base < epos; base += 64) {
        int m = epos - base; if (m > 64) m = 64;
        int2 ent = (lane < m) ? csr[base + lane] : make_int2(0, 0);
        int i = 0;
        for (; i + 4 <= m; i += 4) {
            int   s0 = __shfl(ent.x, i + 0); float n0 = __shfl(__int_as_float(ent.y), i + 0);
            int   s1 = __shfl(ent.x, i + 1); float n1 = __shfl(__int_as_float(ent.y), i + 1);
            int   s2 = __shfl(ent.x, i + 2); float n2 = __shfl(__int_as_float(ent.y), i + 2);
            int   s3 = __shfl(ent.x, i + 3); float n3 = __shfl(__int_as_float(ent.y), i + 3);
            float v0 = bf2f(tab[((size_t)(unsigned)s0 << 6) + lane]);
            float v1 = bf2f(tab[((size_t)(unsigned)s1 << 6) + lane]);
            float v2 = bf2f(tab[((size_t)(unsigned)s2 << 6) + lane]);
            float v3 = bf2f(tab[((size_t)(unsigned)s3 << 6) + lane]);
            a0 += n0 * v0; a1 += n1 * v1; a2 += n2 * v2; a3 += n3 * v3;
        }
        for (; i < m; ++i) {
            int   s0 = __shfl(ent.x, i); float n0 = __shfl(__int_as_float(ent.y), i);
            a0 += n0 * bf2f(tab[((size_t)(unsigned)s0 << 6) + lane]);
        }
    }
    return (a0 + a1) + (a2 + a3);
}

// ---------- aggregation layer1: h1(f32) = relu(sum norm*h1lin[src] + b1) ----------
__global__ __launch_bounds__(256) void k_agg1(const int2* __restrict__ csr, const int* __restrict__ row_start,
                                              const unsigned short* __restrict__ h1lin,
                                              const float* __restrict__ b1,
                                              float* __restrict__ h1, int N) {
    int wid = threadIdx.x >> 6, lane = threadIdx.x & 63;
    int node = blockIdx.x * 4 + wid;
    if (node >= N) return;
    float acc = agg_row_bf16(csr, row_start[node], row_start[node + 1], h1lin, lane);
    h1[(size_t)node * FHID + lane] = fmaxf(acc + b1[lane], 0.f);
}

// ---------- fused agg2 + GEMM2 (no LDS): out = relu((sum norm*h1[src]) @ W2^T + b2) ----------
__global__ __launch_bounds__(256) void k_agg2f(const int2* __restrict__ csr, const int* __restrict__ row_start,
                                               const float* __restrict__ h1, const float2* __restrict__ W2p,
                                               const float* __restrict__ b2, float* __restrict__ out, int N) {
    int wid = threadIdx.x >> 6, lane = threadIdx.x & 63;
    int node = blockIdx.x * 4 + wid;
    if (node >= N) return;
    float acc = agg_row_f32(csr, row_start[node], row_start[node + 1], h1, lane);
    // epilogue: out[node][j] = relu(sum_k acc_k * W2[j][k] + b2[j]), j = lane, lane+64
    float o0 = b2[lane], o1 = b2[lane + 64];
    #pragma unroll 4
    for (int k = 0; k < FHID; ++k) {
        float a = __shfl(acc, k);       // uniform index -> broadcast
        float2 wv = W2p[(size_t)k * 64 + lane];   // coalesced 512B, L1-resident
        o0 += a * wv.x;
        o1 += a * wv.y;
    }
    out[(size_t)node * FIN + lane] = fmaxf(o0, 0.f);
    out[(size_t)node * FIN + 64 + lane] = fmaxf(o1, 0.f);
}

extern "C" void kernel_launch(void* const* d_in, const int* in_sizes, int n_in,
                              void* d_out, int out_size, void* d_ws, size_t ws_size,
                              hipStream_t stream) {
    const float* x  = (const float*)d_in[0];
    const void*  ei = d_in[1];
    const float* w  = (const float*)d_in[2];
    const float* W1 = (const float*)d_in[3];
    const float* b1 = (const float*)d_in[4];
    const float* W2 = (const float*)d_in[5];
    const float* b2 = (const float*)d_in[6];
    float* out = (float*)d_out;
    int N = in_sizes[0] / FIN;
    int E = in_sizes[2];

    char* ws = (char*)d_ws;
    size_t off = 0;
    auto alloc = [&](size_t b) { size_t o = off; off = (off + b + 255) & ~255ULL; return o; };
    int*   flag      = (int*)(ws + alloc(4));
    unsigned int* packed = (unsigned int*)(ws + alloc((size_t)N * 4));
    float* dis       = (float*)(ws + alloc((size_t)N * 4));
    int*   row_start = (int*)(ws + alloc((size_t)(N + 1) * 4));
    int*   partial   = (int*)(ws + alloc(4096));
    float2* W2p      = (float2*)(ws + alloc((size_t)FHID * FHID * 8));
    int2*  csr       = (int2*)(ws + alloc((size_t)E * 8));
    float* h1        = (float*)(ws + alloc((size_t)N * FHID * 4));
    unsigned short* h1lin = (unsigned short*)(ws + alloc((size_t)N * FHID * 2));
    unsigned char* rank = (unsigned char*)h1lin;  // alias: rank (E bytes <= N*128B) dead before k_gemm1 writes h1lin

    hipMemsetAsync(packed, 0, (size_t)N * 4, stream);

    k_detect<<<1, 64, 0, stream>>>((const uint32_t*)ei, flag);

    int eb = (E + 255) / 256;
    k_deg<<<eb, 256, 0, stream>>>(ei, w, packed, rank, flag, E);
    k_dis<<<(N + 255) / 256, 256, 0, stream>>>(packed, dis, N);

    int nparts = (N + CHUNK - 1) / CHUNK;
    k_scan_part<<<nparts, 256, 0, stream>>>(packed, partial, N);
    k_scan_top<<<1, 64, 0, stream>>>(partial, nparts, row_start, N);
    k_scan_chunk<<<nparts, 256, 0, stream>>>(packed, partial, row_start, N);

    k_fill<<<eb, 256, 0, stream>>>(ei, w, dis, row_start, rank, csr, flag, E);
    k_w2p<<<(FHID * FHID + 255) / 256, 256, 0, stream>>>(W2, W2p);

    k_gemm1<<<(N + 31) / 32, 256, 0, stream>>>(x, W1, h1lin, N);
    k_agg1<<<(N + 3) / 4, 256, 0, stream>>>(csr, row_start, h1lin, b1, h1, N);
    k_agg2f<<<(N + 3) / 4, 256, 0, stream>>>(csr, row_start, h1, W2p, b2, out, N);
}

// Round 8
// 1069.403 us; speedup vs baseline: 1.1661x; 1.1081x over previous
//
#include <hip/hip_runtime.h>
#include <stdint.h>

// x[N,128] f32, edge_index[2,E] int32/64, ew[E] f32, W1[64,128], b1[64], W2[128,64], b2[128]
#define FIN 128
#define FHID 64
#define CHUNK 2048
#define FIX_SCALE 65536.0f      // 2^16 fixed point for weighted degree
#define FIX_INV   (1.0f / 65536.0f)

__device__ __forceinline__ float bf2f(unsigned short u) {
    union { unsigned int i; float f; } v; v.i = ((unsigned int)u) << 16; return v.f;
}
__device__ __forceinline__ unsigned short f2bf(float f) {
    union { float f; unsigned int i; } v; v.f = f;
    unsigned int u = v.i;
    u += 0x7FFFu + ((u >> 16) & 1u);   // round-to-nearest-even
    return (unsigned short)(u >> 16);
}

// ---------- dtype detection: int64 edge_index has odd 32-bit words == 0 ----------
__global__ void k_detect(const uint32_t* __restrict__ ei, int* __restrict__ flag) {
    if (blockIdx.x == 0 && threadIdx.x == 0) {
        uint32_t o = 0;
        #pragma unroll
        for (int i = 1; i < 16; i += 2) o |= ei[i];
        *flag = (o == 0) ? 1 : 0;
    }
}

__device__ __forceinline__ int edge_at(const void* ei, long long idx, int is64) {
    if (is64) return (int)((const long long*)ei)[idx];
    return ((const int*)ei)[idx];
}

// ---------- packed degree + per-edge rank: one u32 atomic per edge ----------
// bits [24:31] = count (max deg ~70 << 255), bits [0:23] = wdeg in 2^-16 fixed
// point (max ~70*65536 ~ 4.6M < 2^24). Quantization rel err ~1e-5 on wdeg.
__global__ __launch_bounds__(256) void k_deg(const void* __restrict__ ei, const float* __restrict__ w,
                                             unsigned int* __restrict__ packed,
                                             unsigned char* __restrict__ rank,
                                             const int* __restrict__ flag, int E) {
    int e = blockIdx.x * 256 + threadIdx.x;
    if (e >= E) return;
    int is64 = *flag;
    int c = edge_at(ei, (long long)E + e, is64);
    unsigned int inc = (1u << 24) | __float2uint_rn(w[e] * FIX_SCALE);
    unsigned int old = atomicAdd(&packed[c], inc);
    rank[e] = (unsigned char)(old >> 24);
}

// ---------- packed -> deg^-1/2 ----------
__global__ __launch_bounds__(256) void k_dis(const unsigned int* __restrict__ packed,
                                             float* __restrict__ dis, int N) {
    int i = blockIdx.x * 256 + threadIdx.x;
    if (i < N) {
        float d = (float)(packed[i] & 0xFFFFFFu) * FIX_INV;
        dis[i] = (d > 0.f) ? rsqrtf(d) : 0.f;
    }
}

// ---------- exclusive scan of packed counts -> row_start ----------
__global__ __launch_bounds__(256) void k_scan_part(const unsigned int* __restrict__ packed,
                                                   int* __restrict__ partial, int N) {
    __shared__ int sdata[256];
    int b = blockIdx.x, t = threadIdx.x;
    int base = b * CHUNK;
    int sum = 0;
    #pragma unroll
    for (int q = 0; q < CHUNK / 256; ++q) {
        int idx = base + q * 256 + t;
        if (idx < N) sum += (int)(packed[idx] >> 24);
    }
    sdata[t] = sum; __syncthreads();
    for (int off = 128; off > 0; off >>= 1) {
        if (t < off) sdata[t] += sdata[t + off];
        __syncthreads();
    }
    if (t == 0) partial[b] = sdata[0];
}

__global__ void k_scan_top(int* partial, int nparts, int* row_start, int N) {
    if (blockIdx.x == 0 && threadIdx.x == 0) {
        int run = 0;
        for (int i = 0; i < nparts; ++i) { int v = partial[i]; partial[i] = run; run += v; }
        row_start[N] = run;   // == E
    }
}

__global__ __launch_bounds__(256) void k_scan_chunk(const unsigned int* __restrict__ packed,
                                                    const int* __restrict__ partial,
                                                    int* __restrict__ row_start, int N) {
    __shared__ int tsum[256];
    __shared__ int toff[256];
    int b = blockIdx.x, t = threadIdx.x;
    int base = b * CHUNK + t * 8;
    int v[8]; int s = 0;
    #pragma unroll
    for (int q = 0; q < 8; ++q) {
        int idx = base + q;
        v[q] = (idx < N) ? (int)(packed[idx] >> 24) : 0;
        s += v[q];
    }
    tsum[t] = s; __syncthreads();
    if (t == 0) {
        int run = partial[b];
        for (int i = 0; i < 256; ++i) { int x = tsum[i]; toff[i] = run; run += x; }
    }
    __syncthreads();
    int ex = toff[t];
    #pragma unroll
    for (int q = 0; q < 8; ++q) {
        int idx = base + q;
        if (idx < N) row_start[idx] = ex;
        ex += v[q];
    }
}

// ---------- CSR fill (atomic-free): csr[row_start[c]+rank[e]] = {src, norm} ----------
__global__ __launch_bounds__(256) void k_fill(const void* __restrict__ ei, const float* __restrict__ w,
                                              const float* __restrict__ dis,
                                              const int* __restrict__ row_start,
                                              const unsigned char* __restrict__ rank,
                                              int2* __restrict__ csr,
                                              const int* __restrict__ flag, int E) {
    int e = blockIdx.x * 256 + threadIdx.x;
    if (e >= E) return;
    int is64 = *flag;
    int r = edge_at(ei, e, is64);
    int c = edge_at(ei, (long long)E + e, is64);
    float nm = dis[r] * w[e] * dis[c];
    int pos = row_start[c] + (int)rank[e];
    csr[pos] = make_int2(r, __float_as_int(nm));
}

// ---------- W2 transpose: W2t[k*128+j] = W2[j*64+k] ----------
__global__ __launch_bounds__(256) void k_w2t(const float* __restrict__ W2, float* __restrict__ W2t) {
    int i = blockIdx.x * 256 + threadIdx.x;   // 8192 elements
    if (i < FIN * FHID) {
        int j = i >> 6, k = i & 63;
        W2t[k * FIN + j] = W2[i];
    }
}

// ---------- GEMM1: h1lin[N,64](bf16, deterministic) = x[N,128] @ W1^T ----------
__global__ __launch_bounds__(256, 4) void k_gemm1(const float* __restrict__ x, const float* __restrict__ W1,
                                                  unsigned short* __restrict__ h1lin, int N) {
    __shared__ float Wt[FIN * 65];      // Wt[k*65+j] = W1[j*128+k], padded: conflict-free
    __shared__ float xt[32 * FIN];      // 16 KB
    int t = threadIdx.x;
    for (int i = t; i < FHID * FIN; i += 256) {
        int j = i >> 7, k = i & 127;
        Wt[k * 65 + j] = W1[i];         // lane-varying k -> stride 65 -> conflict-free
    }
    int r0 = blockIdx.x * 32;
    const float4* xg = (const float4*)(x + (size_t)r0 * FIN);
    float4* xt4 = (float4*)xt;
    #pragma unroll
    for (int q = 0; q < 4; ++q) {
        int i = t + q * 256;            // 1024 float4 total, 32 per row
        if (r0 + (i >> 5) < N) xt4[i] = xg[i];
    }
    __syncthreads();
    int j = t & 63, rg = t >> 6;        // rg uniform per wave
    float acc[8];
    #pragma unroll
    for (int r = 0; r < 8; ++r) acc[r] = 0.f;
    for (int kk = 0; kk < FIN; kk += 4) {
        float w0 = Wt[(kk + 0) * 65 + j];
        float w1 = Wt[(kk + 1) * 65 + j];
        float w2 = Wt[(kk + 2) * 65 + j];
        float w3 = Wt[(kk + 3) * 65 + j];
        #pragma unroll
        for (int r = 0; r < 8; ++r) {
            float4 xv = xt4[(rg * 8 + r) * 32 + (kk >> 2)];
            acc[r] += xv.x * w0 + xv.y * w1 + xv.z * w2 + xv.w * w3;
        }
    }
    #pragma unroll
    for (int r = 0; r < 8; ++r) {
        int row = r0 + rg * 8 + r;
        if (row < N) h1lin[(size_t)row * FHID + j] = f2bf(acc[r]);
    }
}

// ---------- gather-accumulate, 4 chains, 32-bit index arithmetic (round-4 form) ----------
__device__ __forceinline__ float agg_row_f32(const int2* __restrict__ csr, int s, int epos,
                                             const float* __restrict__ tab, int lane) {
    float a0 = 0.f, a1 = 0.f, a2 = 0.f, a3 = 0.f;
    for (int base = s; base < epos; base += 64) {
        int m = epos - base; if (m > 64) m = 64;
        int2 ent = (lane < m) ? csr[base + lane] : make_int2(0, 0);
        int i = 0;
        for (; i + 4 <= m; i += 4) {
            int   s0 = __shfl(ent.x, i + 0); float n0 = __shfl(__int_as_float(ent.y), i + 0);
            int   s1 = __shfl(ent.x, i + 1); float n1 = __shfl(__int_as_float(ent.y), i + 1);
            int   s2 = __shfl(ent.x, i + 2); float n2 = __shfl(__int_as_float(ent.y), i + 2);
            int   s3 = __shfl(ent.x, i + 3); float n3 = __shfl(__int_as_float(ent.y), i + 3);
            float v0 = tab[(size_t)((unsigned)s0 << 6) + lane];
            float v1 = tab[(size_t)((unsigned)s1 << 6) + lane];
            float v2 = tab[(size_t)((unsigned)s2 << 6) + lane];
            float v3 = tab[(size_t)((unsigned)s3 << 6) + lane];
            a0 += n0 * v0; a1 += n1 * v1; a2 += n2 * v2; a3 += n3 * v3;
        }
        for (; i < m; ++i) {
            int   s0 = __shfl(ent.x, i); float n0 = __shfl(__int_as_float(ent.y), i);
            a0 += n0 * tab[(size_t)((unsigned)s0 << 6) + lane];
        }
    }
    return (a0 + a1) + (a2 + a3);
}

__device__ __forceinline__ float agg_row_bf16(const int2* __restrict__ csr, int s, int epos,
                                              const unsigned short* __restrict__ tab, int lane) {
    float a0 = 0.f, a1 = 0.f, a2 = 0.f, a3 = 0.f;
    for (int base = s; base < epos; base += 64) {
        int m = epos - base; if (m > 64) m = 64;
        int2 ent = (lane < m) ? csr[base + lane] : make_int2(0, 0);
        int i = 0;
        for (; i + 4 <= m; i += 4) {
            int   s0 = __shfl(ent.x, i + 0); float n0 = __shfl(__int_as_float(ent.y), i + 0);
            int   s1 = __shfl(ent.x, i + 1); float n1 = __shfl(__int_as_float(ent.y), i + 1);
            int   s2 = __shfl(ent.x, i + 2); float n2 = __shfl(__int_as_float(ent.y), i + 2);
            int   s3 = __shfl(ent.x, i + 3); float n3 = __shfl(__int_as_float(ent.y), i + 3);
            float v0 = bf2f(tab[(size_t)((unsigned)s0 << 6) + lane]);
            float v1 = bf2f(tab[(size_t)((unsigned)s1 << 6) + lane]);
            float v2 = bf2f(tab[(size_t)((unsigned)s2 << 6) + lane]);
            float v3 = bf2f(tab[(size_t)((unsigned)s3 << 6) + lane]);
            a0 += n0 * v0; a1 += n1 * v1; a2 += n2 * v2; a3 += n3 * v3;
        }
        for (; i < m; ++i) {
            int   s0 = __shfl(ent.x, i); float n0 = __shfl(__int_as_float(ent.y), i);
            a0 += n0 * bf2f(tab[(size_t)((unsigned)s0 << 6) + lane]);
        }
    }
    return (a0 + a1) + (a2 + a3);
}

// ---------- aggregation layer1: h1(f32) = relu(sum norm*h1lin[src] + b1) ----------
__global__ __launch_bounds__(256) void k_agg1(const int2* __restrict__ csr, const int* __restrict__ row_start,
                                              const unsigned short* __restrict__ h1lin,
                                              const float* __restrict__ b1,
                                              float* __restrict__ h1, int N) {
    int wid = threadIdx.x >> 6, lane = threadIdx.x & 63;
    int node = blockIdx.x * 4 + wid;
    if (node >= N) return;
    float acc = agg_row_bf16(csr, row_start[node], row_start[node + 1], h1lin, lane);
    h1[(size_t)node * FHID + lane] = fmaxf(acc + b1[lane], 0.f);
}

// ---------- fused agg2 + GEMM2 (no LDS): out = relu((sum norm*h1[src]) @ W2^T + b2) ----------
__global__ __launch_bounds__(256) void k_agg2f(const int2* __restrict__ csr, const int* __restrict__ row_start,
                                               const float* __restrict__ h1, const float* __restrict__ W2t,
                                               const float* __restrict__ b2, float* __restrict__ out, int N) {
    int wid = threadIdx.x >> 6, lane = threadIdx.x & 63;
    int node = blockIdx.x * 4 + wid;
    if (node >= N) return;
    float acc = agg_row_f32(csr, row_start[node], row_start[node + 1], h1, lane);
    // epilogue: out[node][j] = relu(sum_k acc_k * W2[j][k] + b2[j]), j = lane, lane+64
    float o0 = b2[lane], o1 = b2[lane + 64];
    #pragma unroll 4
    for (int k = 0; k < FHID; ++k) {
        float a = __shfl(acc, k);       // uniform index -> broadcast
        o0 += a * W2t[k * FIN + lane];          // coalesced 256B, L1-resident
        o1 += a * W2t[k * FIN + 64 + lane];
    }
    out[(size_t)node * FIN + lane] = fmaxf(o0, 0.f);
    out[(size_t)node * FIN + 64 + lane] = fmaxf(o1, 0.f);
}

extern "C" void kernel_launch(void* const* d_in, const int* in_sizes, int n_in,
                              void* d_out, int out_size, void* d_ws, size_t ws_size,
                              hipStream_t stream) {
    const float* x  = (const float*)d_in[0];
    const void*  ei = d_in[1];
    const float* w  = (const float*)d_in[2];
    const float* W1 = (const float*)d_in[3];
    const float* b1 = (const float*)d_in[4];
    const float* W2 = (const float*)d_in[5];
    const float* b2 = (const float*)d_in[6];
    float* out = (float*)d_out;
    int N = in_sizes[0] / FIN;
    int E = in_sizes[2];

    char* ws = (char*)d_ws;
    size_t off = 0;
    auto alloc = [&](size_t b) { size_t o = off; off = (off + b + 255) & ~255ULL; return o; };
    int*   flag      = (int*)(ws + alloc(4));
    unsigned int* packed = (unsigned int*)(ws + alloc((size_t)N * 4));
    float* dis       = (float*)(ws + alloc((size_t)N * 4));
    int*   row_start = (int*)(ws + alloc((size_t)(N + 1) * 4));
    int*   partial   = (int*)(ws + alloc(4096));
    float* W2t       = (float*)(ws + alloc((size_t)FIN * FHID * 4));
    int2*  csr       = (int2*)(ws + alloc((size_t)E * 8));
    float* h1        = (float*)(ws + alloc((size_t)N * FHID * 4));
    unsigned short* h1lin = (unsigned short*)(ws + alloc((size_t)N * FHID * 2));
    unsigned char* rank = (unsigned char*)h1lin;  // alias: rank (E bytes <= N*128B) dead before k_gemm1 writes h1lin

    hipMemsetAsync(packed, 0, (size_t)N * 4, stream);

    k_detect<<<1, 64, 0, stream>>>((const uint32_t*)ei, flag);

    int eb = (E + 255) / 256;
    k_deg<<<eb, 256, 0, stream>>>(ei, w, packed, rank, flag, E);
    k_dis<<<(N + 255) / 256, 256, 0, stream>>>(packed, dis, N);

    int nparts = (N + CHUNK - 1) / CHUNK;
    k_scan_part<<<nparts, 256, 0, stream>>>(packed, partial, N);
    k_scan_top<<<1, 64, 0, stream>>>(partial, nparts, row_start, N);
    k_scan_chunk<<<nparts, 256, 0, stream>>>(packed, partial, row_start, N);

    k_fill<<<eb, 256, 0, stream>>>(ei, w, dis, row_start, rank, csr, flag, E);
    k_w2t<<<(FIN * FHID + 255) / 256, 256, 0, stream>>>(W2, W2t);

    k_gemm1<<<(N + 31) / 32, 256, 0, stream>>>(x, W1, h1lin, N);
    k_agg1<<<(N + 3) / 4, 256, 0, stream>>>(csr, row_start, h1lin, b1, h1, N);
    k_agg2f<<<(N + 3) / 4, 256, 0, stream>>>(csr, row_start, h1, W2t, b2, out, N);
}

// Round 9
// 1051.714 us; speedup vs baseline: 1.1857x; 1.0168x over previous
//
#include <hip/hip_runtime.h>
#include <stdint.h>

// x[N,128] f32, edge_index[2,E] int32/64, ew[E] f32, W1[64,128], b1[64], W2[128,64], b2[128]
#define FIN 128
#define FHID 64
#define CHUNK 2048
#define FIX_SCALE 65536.0f      // 2^16 fixed point for weighted degree
#define FIX_INV   (1.0f / 65536.0f)
#define AGG_SC    262144.0f     // 2^18 fixed point for order-invariant agg1
#define AGG_INV   (1.0f / 262144.0f)

__device__ __forceinline__ float bf2f(unsigned short u) {
    union { unsigned int i; float f; } v; v.i = ((unsigned int)u) << 16; return v.f;
}
__device__ __forceinline__ unsigned short f2bf(float f) {
    union { float f; unsigned int i; } v; v.f = f;
    unsigned int u = v.i;
    u += 0x7FFFu + ((u >> 16) & 1u);   // round-to-nearest-even
    return (unsigned short)(u >> 16);
}

// ---------- dtype detection: int64 edge_index has odd 32-bit words == 0 ----------
__global__ void k_detect(const uint32_t* __restrict__ ei, int* __restrict__ flag) {
    if (blockIdx.x == 0 && threadIdx.x == 0) {
        uint32_t o = 0;
        #pragma unroll
        for (int i = 1; i < 16; i += 2) o |= ei[i];
        *flag = (o == 0) ? 1 : 0;
    }
}

__device__ __forceinline__ int edge_at(const void* ei, long long idx, int is64) {
    if (is64) return (int)((const long long*)ei)[idx];
    return ((const int*)ei)[idx];
}

// ---------- packed degree + per-edge rank: one u32 atomic per edge ----------
// bits [24:31] = count (max deg ~70 << 255), bits [0:23] = wdeg in 2^-16 fixed
// point (max ~70*65536 ~ 4.6M < 2^24). Quantization rel err ~1e-5 on wdeg.
__global__ __launch_bounds__(256) void k_deg(const void* __restrict__ ei, const float* __restrict__ w,
                                             unsigned int* __restrict__ packed,
                                             unsigned char* __restrict__ rank,
                                             const int* __restrict__ flag, int E) {
    int e = blockIdx.x * 256 + threadIdx.x;
    if (e >= E) return;
    int is64 = *flag;
    int c = edge_at(ei, (long long)E + e, is64);
    unsigned int inc = (1u << 24) | __float2uint_rn(w[e] * FIX_SCALE);
    unsigned int old = atomicAdd(&packed[c], inc);
    rank[e] = (unsigned char)(old >> 24);
}

// ---------- packed -> deg^-1/2 ----------
__global__ __launch_bounds__(256) void k_dis(const unsigned int* __restrict__ packed,
                                             float* __restrict__ dis, int N) {
    int i = blockIdx.x * 256 + threadIdx.x;
    if (i < N) {
        float d = (float)(packed[i] & 0xFFFFFFu) * FIX_INV;
        dis[i] = (d > 0.f) ? rsqrtf(d) : 0.f;
    }
}

// ---------- exclusive scan of packed counts -> row_start ----------
__global__ __launch_bounds__(256) void k_scan_part(const unsigned int* __restrict__ packed,
                                                   int* __restrict__ partial, int N) {
    __shared__ int sdata[256];
    int b = blockIdx.x, t = threadIdx.x;
    int base = b * CHUNK;
    int sum = 0;
    #pragma unroll
    for (int q = 0; q < CHUNK / 256; ++q) {
        int idx = base + q * 256 + t;
        if (idx < N) sum += (int)(packed[idx] >> 24);
    }
    sdata[t] = sum; __syncthreads();
    for (int off = 128; off > 0; off >>= 1) {
        if (t < off) sdata[t] += sdata[t + off];
        __syncthreads();
    }
    if (t == 0) partial[b] = sdata[0];
}

__global__ void k_scan_top(int* partial, int nparts, int* row_start, int N) {
    if (blockIdx.x == 0 && threadIdx.x == 0) {
        int run = 0;
        for (int i = 0; i < nparts; ++i) { int v = partial[i]; partial[i] = run; run += v; }
        row_start[N] = run;   // == E
    }
}

__global__ __launch_bounds__(256) void k_scan_chunk(const unsigned int* __restrict__ packed,
                                                    const int* __restrict__ partial,
                                                    int* __restrict__ row_start, int N) {
    __shared__ int tsum[256];
    __shared__ int toff[256];
    int b = blockIdx.x, t = threadIdx.x;
    int base = b * CHUNK + t * 8;
    int v[8]; int s = 0;
    #pragma unroll
    for (int q = 0; q < 8; ++q) {
        int idx = base + q;
        v[q] = (idx < N) ? (int)(packed[idx] >> 24) : 0;
        s += v[q];
    }
    tsum[t] = s; __syncthreads();
    if (t == 0) {
        int run = partial[b];
        for (int i = 0; i < 256; ++i) { int x = tsum[i]; toff[i] = run; run += x; }
    }
    __syncthreads();
    int ex = toff[t];
    #pragma unroll
    for (int q = 0; q < 8; ++q) {
        int idx = base + q;
        if (idx < N) row_start[idx] = ex;
        ex += v[q];
    }
}

// ---------- CSR fill (atomic-free): csr[row_start[c]+rank[e]] = {src, norm} ----------
__global__ __launch_bounds__(256) void k_fill(const void* __restrict__ ei, const float* __restrict__ w,
                                              const float* __restrict__ dis,
                                              const int* __restrict__ row_start,
                                              const unsigned char* __restrict__ rank,
                                              int2* __restrict__ csr,
                                              const int* __restrict__ flag, int E) {
    int e = blockIdx.x * 256 + threadIdx.x;
    if (e >= E) return;
    int is64 = *flag;
    int r = edge_at(ei, e, is64);
    int c = edge_at(ei, (long long)E + e, is64);
    float nm = dis[r] * w[e] * dis[c];
    int pos = row_start[c] + (int)rank[e];
    csr[pos] = make_int2(r, __float_as_int(nm));
}

// ---------- W2 transpose: W2t[k*128+j] = W2[j*64+k] ----------
__global__ __launch_bounds__(256) void k_w2t(const float* __restrict__ W2, float* __restrict__ W2t) {
    int i = blockIdx.x * 256 + threadIdx.x;   // 8192 elements
    if (i < FIN * FHID) {
        int j = i >> 6, k = i & 63;
        W2t[k * FIN + j] = W2[i];
    }
}

// ---------- GEMM1: h1lin[N,64](bf16, deterministic) = x[N,128] @ W1^T ----------
__global__ __launch_bounds__(256, 4) void k_gemm1(const float* __restrict__ x, const float* __restrict__ W1,
                                                  unsigned short* __restrict__ h1lin, int N) {
    __shared__ float Wt[FIN * 65];      // Wt[k*65+j] = W1[j*128+k], padded: conflict-free
    __shared__ float xt[32 * FIN];      // 16 KB
    int t = threadIdx.x;
    for (int i = t; i < FHID * FIN; i += 256) {
        int j = i >> 7, k = i & 127;
        Wt[k * 65 + j] = W1[i];         // lane-varying k -> stride 65 -> conflict-free
    }
    int r0 = blockIdx.x * 32;
    const float4* xg = (const float4*)(x + (size_t)r0 * FIN);
    float4* xt4 = (float4*)xt;
    #pragma unroll
    for (int q = 0; q < 4; ++q) {
        int i = t + q * 256;            // 1024 float4 total, 32 per row
        if (r0 + (i >> 5) < N) xt4[i] = xg[i];
    }
    __syncthreads();
    int j = t & 63, rg = t >> 6;        // rg uniform per wave
    float acc[8];
    #pragma unroll
    for (int r = 0; r < 8; ++r) acc[r] = 0.f;
    for (int kk = 0; kk < FIN; kk += 4) {
        float w0 = Wt[(kk + 0) * 65 + j];
        float w1 = Wt[(kk + 1) * 65 + j];
        float w2 = Wt[(kk + 2) * 65 + j];
        float w3 = Wt[(kk + 3) * 65 + j];
        #pragma unroll
        for (int r = 0; r < 8; ++r) {
            float4 xv = xt4[(rg * 8 + r) * 32 + (kk >> 2)];
            acc[r] += xv.x * w0 + xv.y * w1 + xv.z * w2 + xv.w * w3;
        }
    }
    #pragma unroll
    for (int r = 0; r < 8; ++r) {
        int row = r0 + rg * 8 + r;
        if (row < N) h1lin[(size_t)row * FHID + j] = f2bf(acc[r]);
    }
}

// ---------- order-INVARIANT gather-accumulate (int32 fixed point, bf16 table) ----------
// Integer adds are exactly commutative -> result independent of CSR row
// permutation (which varies per launch via k_deg's atomic arrival order).
__device__ __forceinline__ float agg_row_fx(const int2* __restrict__ csr, int s, int epos,
                                            const unsigned short* __restrict__ tab, int lane) {
    int a0 = 0, a1 = 0, a2 = 0, a3 = 0;
    for (int base = s; base < epos; base += 64) {
        int m = epos - base; if (m > 64) m = 64;
        int2 ent = (lane < m) ? csr[base + lane] : make_int2(0, 0);
        int i = 0;
        for (; i + 4 <= m; i += 4) {
            int   s0 = __shfl(ent.x, i + 0); float n0 = __shfl(__int_as_float(ent.y), i + 0);
            int   s1 = __shfl(ent.x, i + 1); float n1 = __shfl(__int_as_float(ent.y), i + 1);
            int   s2 = __shfl(ent.x, i + 2); float n2 = __shfl(__int_as_float(ent.y), i + 2);
            int   s3 = __shfl(ent.x, i + 3); float n3 = __shfl(__int_as_float(ent.y), i + 3);
            float v0 = bf2f(tab[(size_t)((unsigned)s0 << 6) + lane]);
            float v1 = bf2f(tab[(size_t)((unsigned)s1 << 6) + lane]);
            float v2 = bf2f(tab[(size_t)((unsigned)s2 << 6) + lane]);
            float v3 = bf2f(tab[(size_t)((unsigned)s3 << 6) + lane]);
            a0 += __float2int_rz((n0 * AGG_SC) * v0);
            a1 += __float2int_rz((n1 * AGG_SC) * v1);
            a2 += __float2int_rz((n2 * AGG_SC) * v2);
            a3 += __float2int_rz((n3 * AGG_SC) * v3);
        }
        for (; i < m; ++i) {
            int   s0 = __shfl(ent.x, i); float n0 = __shfl(__int_as_float(ent.y), i);
            a0 += __float2int_rz((n0 * AGG_SC) * bf2f(tab[(size_t)((unsigned)s0 << 6) + lane]));
        }
    }
    return (float)((a0 + a1) + (a2 + a3)) * AGG_INV;
}

// ---------- gather-accumulate, 4 chains, f32 accumulation, bf16 table ----------
__device__ __forceinline__ float agg_row_bf16(const int2* __restrict__ csr, int s, int epos,
                                              const unsigned short* __restrict__ tab, int lane) {
    float a0 = 0.f, a1 = 0.f, a2 = 0.f, a3 = 0.f;
    for (int base = s; base < epos; base += 64) {
        int m = epos - base; if (m > 64) m = 64;
        int2 ent = (lane < m) ? csr[base + lane] : make_int2(0, 0);
        int i = 0;
        for (; i + 4 <= m; i += 4) {
            int   s0 = __shfl(ent.x, i + 0); float n0 = __shfl(__int_as_float(ent.y), i + 0);
            int   s1 = __shfl(ent.x, i + 1); float n1 = __shfl(__int_as_float(ent.y), i + 1);
            int   s2 = __shfl(ent.x, i + 2); float n2 = __shfl(__int_as_float(ent.y), i + 2);
            int   s3 = __shfl(ent.x, i + 3); float n3 = __shfl(__int_as_float(ent.y), i + 3);
            float v0 = bf2f(tab[(size_t)((unsigned)s0 << 6) + lane]);
            float v1 = bf2f(tab[(size_t)((unsigned)s1 << 6) + lane]);
            float v2 = bf2f(tab[(size_t)((unsigned)s2 << 6) + lane]);
            float v3 = bf2f(tab[(size_t)((unsigned)s3 << 6) + lane]);
            a0 += n0 * v0; a1 += n1 * v1; a2 += n2 * v2; a3 += n3 * v3;
        }
        for (; i < m; ++i) {
            int   s0 = __shfl(ent.x, i); float n0 = __shfl(__int_as_float(ent.y), i);
            a0 += n0 * bf2f(tab[(size_t)((unsigned)s0 << 6) + lane]);
        }
    }
    return (a0 + a1) + (a2 + a3);
}

// ---------- aggregation layer1: h1(bf16, deterministic) = relu(sum + b1) ----------
__global__ __launch_bounds__(256) void k_agg1(const int2* __restrict__ csr, const int* __restrict__ row_start,
                                              const unsigned short* __restrict__ h1lin,
                                              const float* __restrict__ b1,
                                              unsigned short* __restrict__ h1, int N) {
    int wid = threadIdx.x >> 6, lane = threadIdx.x & 63;
    int node = blockIdx.x * 4 + wid;
    if (node >= N) return;
    float acc = agg_row_fx(csr, row_start[node], row_start[node + 1], h1lin, lane);
    h1[(size_t)node * FHID + lane] = f2bf(fmaxf(acc + b1[lane], 0.f));
}

// ---------- fused agg2 + GEMM2 (no LDS): out = relu((sum norm*h1[src]) @ W2^T + b2) ----------
__global__ __launch_bounds__(256) void k_agg2f(const int2* __restrict__ csr, const int* __restrict__ row_start,
                                               const unsigned short* __restrict__ h1,
                                               const float* __restrict__ W2t,
                                               const float* __restrict__ b2, float* __restrict__ out, int N) {
    int wid = threadIdx.x >> 6, lane = threadIdx.x & 63;
    int node = blockIdx.x * 4 + wid;
    if (node >= N) return;
    float acc = agg_row_bf16(csr, row_start[node], row_start[node + 1], h1, lane);
    // epilogue: out[node][j] = relu(sum_k acc_k * W2[j][k] + b2[j]), j = lane, lane+64
    float o0 = b2[lane], o1 = b2[lane + 64];
    #pragma unroll 4
    for (int k = 0; k < FHID; ++k) {
        float a = __shfl(acc, k);       // uniform index -> broadcast
        o0 += a * W2t[k * FIN + lane];          // coalesced 256B, L1-resident
        o1 += a * W2t[k * FIN + 64 + lane];
    }
    out[(size_t)node * FIN + lane] = fmaxf(o0, 0.f);
    out[(size_t)node * FIN + 64 + lane] = fmaxf(o1, 0.f);
}

extern "C" void kernel_launch(void* const* d_in, const int* in_sizes, int n_in,
                              void* d_out, int out_size, void* d_ws, size_t ws_size,
                              hipStream_t stream) {
    const float* x  = (const float*)d_in[0];
    const void*  ei = d_in[1];
    const float* w  = (const float*)d_in[2];
    const float* W1 = (const float*)d_in[3];
    const float* b1 = (const float*)d_in[4];
    const float* W2 = (const float*)d_in[5];
    const float* b2 = (const float*)d_in[6];
    float* out = (float*)d_out;
    int N = in_sizes[0] / FIN;
    int E = in_sizes[2];

    char* ws = (char*)d_ws;
    size_t off = 0;
    auto alloc = [&](size_t b) { size_t o = off; off = (off + b + 255) & ~255ULL; return o; };
    int*   flag      = (int*)(ws + alloc(4));
    unsigned int* packed = (unsigned int*)(ws + alloc((size_t)N * 4));
    float* dis       = (float*)(ws + alloc((size_t)N * 4));
    int*   row_start = (int*)(ws + alloc((size_t)(N + 1) * 4));
    int*   partial   = (int*)(ws + alloc(4096));
    float* W2t       = (float*)(ws + alloc((size_t)FIN * FHID * 4));
    int2*  csr       = (int2*)(ws + alloc((size_t)E * 8));
    unsigned short* h1    = (unsigned short*)(ws + alloc((size_t)N * FHID * 2));
    unsigned short* h1lin = (unsigned short*)(ws + alloc((size_t)N * FHID * 2));
    unsigned char* rank = (unsigned char*)h1lin;  // alias: rank (E bytes <= N*128B) dead before k_gemm1 writes h1lin

    hipMemsetAsync(packed, 0, (size_t)N * 4, stream);

    k_detect<<<1, 64, 0, stream>>>((const uint32_t*)ei, flag);

    int eb = (E + 255) / 256;
    k_deg<<<eb, 256, 0, stream>>>(ei, w, packed, rank, flag, E);
    k_dis<<<(N + 255) / 256, 256, 0, stream>>>(packed, dis, N);

    int nparts = (N + CHUNK - 1) / CHUNK;
    k_scan_part<<<nparts, 256, 0, stream>>>(packed, partial, N);
    k_scan_top<<<1, 64, 0, stream>>>(partial, nparts, row_start, N);
    k_scan_chunk<<<nparts, 256, 0, stream>>>(packed, partial, row_start, N);

    k_fill<<<eb, 256, 0, stream>>>(ei, w, dis, row_start, rank, csr, flag, E);
    k_w2t<<<(FIN * FHID + 255) / 256, 256, 0, stream>>>(W2, W2t);

    k_gemm1<<<(N + 31) / 32, 256, 0, stream>>>(x, W1, h1lin, N);
    k_agg1<<<(N + 3) / 4, 256, 0, stream>>>(csr, row_start, h1lin, b1, h1, N);
    k_agg2f<<<(N + 3) / 4, 256, 0, stream>>>(csr, row_start, h1, W2t, b2, out, N);
}

// Round 10
// 1009.797 us; speedup vs baseline: 1.2349x; 1.0415x over previous
//
#include <hip/hip_runtime.h>
#include <stdint.h>

// x[N,128] f32, edge_index[2,E] int32/64, ew[E] f32, W1[64,128], b1[64], W2[128,64], b2[128]
#define FIN 128
#define FHID 64
#define CHUNK 2048
#define FIX_SCALE 65536.0f      // 2^16 fixed point for weighted degree
#define FIX_INV   (1.0f / 65536.0f)
#define AGG_SC    262144.0f     // 2^18 fixed point for order-invariant agg1
#define AGG_INV   (1.0f / 262144.0f)

__device__ __forceinline__ float bf2f(unsigned short u) {
    union { unsigned int i; float f; } v; v.i = ((unsigned int)u) << 16; return v.f;
}
__device__ __forceinline__ unsigned short f2bf(float f) {
    union { float f; unsigned int i; } v; v.f = f;
    unsigned int u = v.i;
    u += 0x7FFFu + ((u >> 16) & 1u);   // round-to-nearest-even
    return (unsigned short)(u >> 16);
}

// ---------- dtype detection: int64 edge_index has odd 32-bit words == 0 ----------
__global__ void k_detect(const uint32_t* __restrict__ ei, int* __restrict__ flag) {
    if (blockIdx.x == 0 && threadIdx.x == 0) {
        uint32_t o = 0;
        #pragma unroll
        for (int i = 1; i < 16; i += 2) o |= ei[i];
        *flag = (o == 0) ? 1 : 0;
    }
}

__device__ __forceinline__ int edge_at(const void* ei, long long idx, int is64) {
    if (is64) return (int)((const long long*)ei)[idx];
    return ((const int*)ei)[idx];
}

// ---------- packed degree + per-edge rank: one u32 atomic per edge ----------
__global__ __launch_bounds__(256) void k_deg(const void* __restrict__ ei, const float* __restrict__ w,
                                             unsigned int* __restrict__ packed,
                                             unsigned char* __restrict__ rank,
                                             const int* __restrict__ flag, int E) {
    int e = blockIdx.x * 256 + threadIdx.x;
    if (e >= E) return;
    int is64 = *flag;
    int c = edge_at(ei, (long long)E + e, is64);
    unsigned int inc = (1u << 24) | __float2uint_rn(w[e] * FIX_SCALE);
    unsigned int old = atomicAdd(&packed[c], inc);
    rank[e] = (unsigned char)(old >> 24);
}

// ---------- packed -> deg^-1/2 ----------
__global__ __launch_bounds__(256) void k_dis(const unsigned int* __restrict__ packed,
                                             float* __restrict__ dis, int N) {
    int i = blockIdx.x * 256 + threadIdx.x;
    if (i < N) {
        float d = (float)(packed[i] & 0xFFFFFFu) * FIX_INV;
        dis[i] = (d > 0.f) ? rsqrtf(d) : 0.f;
    }
}

// ---------- exclusive scan of packed counts -> row_start ----------
__global__ __launch_bounds__(256) void k_scan_part(const unsigned int* __restrict__ packed,
                                                   int* __restrict__ partial, int N) {
    __shared__ int sdata[256];
    int b = blockIdx.x, t = threadIdx.x;
    int base = b * CHUNK;
    int sum = 0;
    #pragma unroll
    for (int q = 0; q < CHUNK / 256; ++q) {
        int idx = base + q * 256 + t;
        if (idx < N) sum += (int)(packed[idx] >> 24);
    }
    sdata[t] = sum; __syncthreads();
    for (int off = 128; off > 0; off >>= 1) {
        if (t < off) sdata[t] += sdata[t + off];
        __syncthreads();
    }
    if (t == 0) partial[b] = sdata[0];
}

__global__ void k_scan_top(int* partial, int nparts, int* row_start, int N) {
    if (blockIdx.x == 0 && threadIdx.x == 0) {
        int run = 0;
        for (int i = 0; i < nparts; ++i) { int v = partial[i]; partial[i] = run; run += v; }
        row_start[N] = run;   // == E
    }
}

__global__ __launch_bounds__(256) void k_scan_chunk(const unsigned int* __restrict__ packed,
                                                    const int* __restrict__ partial,
                                                    int* __restrict__ row_start, int N) {
    __shared__ int tsum[256];
    __shared__ int toff[256];
    int b = blockIdx.x, t = threadIdx.x;
    int base = b * CHUNK + t * 8;
    int v[8]; int s = 0;
    #pragma unroll
    for (int q = 0; q < 8; ++q) {
        int idx = base + q;
        v[q] = (idx < N) ? (int)(packed[idx] >> 24) : 0;
        s += v[q];
    }
    tsum[t] = s; __syncthreads();
    if (t == 0) {
        int run = partial[b];
        for (int i = 0; i < 256; ++i) { int x = tsum[i]; toff[i] = run; run += x; }
    }
    __syncthreads();
    int ex = toff[t];
    #pragma unroll
    for (int q = 0; q < 8; ++q) {
        int idx = base + q;
        if (idx < N) row_start[idx] = ex;
        ex += v[q];
    }
}

// ---------- CSR fill (atomic-free): csr[row_start[c]+rank[e]] = {src, norm} ----------
__global__ __launch_bounds__(256) void k_fill(const void* __restrict__ ei, const float* __restrict__ w,
                                              const float* __restrict__ dis,
                                              const int* __restrict__ row_start,
                                              const unsigned char* __restrict__ rank,
                                              int2* __restrict__ csr,
                                              const int* __restrict__ flag, int E) {
    int e = blockIdx.x * 256 + threadIdx.x;
    if (e >= E) return;
    int is64 = *flag;
    int r = edge_at(ei, e, is64);
    int c = edge_at(ei, (long long)E + e, is64);
    float nm = dis[r] * w[e] * dis[c];
    int pos = row_start[c] + (int)rank[e];
    csr[pos] = make_int2(r, __float_as_int(nm));
}

// ---------- W2 transpose: W2t[k*128+j] = W2[j*64+k] ----------
__global__ __launch_bounds__(256) void k_w2t(const float* __restrict__ W2, float* __restrict__ W2t) {
    int i = blockIdx.x * 256 + threadIdx.x;   // 8192 elements
    if (i < FIN * FHID) {
        int j = i >> 6, k = i & 63;
        W2t[k * FIN + j] = W2[i];
    }
}

// ---------- GEMM1: h1lin[N,64](bf16, deterministic) = x[N,128] @ W1^T ----------
__global__ __launch_bounds__(256, 4) void k_gemm1(const float* __restrict__ x, const float* __restrict__ W1,
                                                  unsigned short* __restrict__ h1lin, int N) {
    __shared__ float Wt[FIN * 65];      // Wt[k*65+j] = W1[j*128+k], padded: conflict-free
    __shared__ float xt[32 * FIN];      // 16 KB
    int t = threadIdx.x;
    for (int i = t; i < FHID * FIN; i += 256) {
        int j = i >> 7, k = i & 127;
        Wt[k * 65 + j] = W1[i];         // lane-varying k -> stride 65 -> conflict-free
    }
    int r0 = blockIdx.x * 32;
    const float4* xg = (const float4*)(x + (size_t)r0 * FIN);
    float4* xt4 = (float4*)xt;
    #pragma unroll
    for (int q = 0; q < 4; ++q) {
        int i = t + q * 256;            // 1024 float4 total, 32 per row
        if (r0 + (i >> 5) < N) xt4[i] = xg[i];
    }
    __syncthreads();
    int j = t & 63, rg = t >> 6;        // rg uniform per wave
    float acc[8];
    #pragma unroll
    for (int r = 0; r < 8; ++r) acc[r] = 0.f;
    for (int kk = 0; kk < FIN; kk += 4) {
        float w0 = Wt[(kk + 0) * 65 + j];
        float w1 = Wt[(kk + 1) * 65 + j];
        float w2 = Wt[(kk + 2) * 65 + j];
        float w3 = Wt[(kk + 3) * 65 + j];
        #pragma unroll
        for (int r = 0; r < 8; ++r) {
            float4 xv = xt4[(rg * 8 + r) * 32 + (kk >> 2)];
            acc[r] += xv.x * w0 + xv.y * w1 + xv.z * w2 + xv.w * w3;
        }
    }
    #pragma unroll
    for (int r = 0; r < 8; ++r) {
        int row = r0 + rg * 8 + r;
        if (row < N) h1lin[(size_t)row * FHID + j] = f2bf(acc[r]);
    }
}

// ---------- pair gather: 2 edges per gather instr, u32 = 2 bf16 per lane ----------
// lanes 0-31 take edge i, lanes 32-63 take edge i+1; lane holds features
// (2*lpos, 2*lpos+1). Cross-half __shfl_xor(32) merges edge subsets.
// Fixed-point (order-invariant) variant for layer 1:
__device__ __forceinline__ float2 agg_row_pair_fx(const int2* __restrict__ csr, int s, int epos,
                                                  const unsigned int* __restrict__ tab32, int lane) {
    int a0x = 0, a0y = 0, a1x = 0, a1y = 0;
    int half = lane >> 5, lpos = lane & 31;
    for (int base = s; base < epos; base += 64) {
        int m = epos - base; if (m > 64) m = 64;
        int2 ent = (lane < m) ? csr[base + lane] : make_int2(0, 0);
        int i = 0;
        for (; i + 4 <= m; i += 4) {
            int   s0 = __shfl(ent.x, i + half);     float n0 = __shfl(__int_as_float(ent.y), i + half);
            int   s1 = __shfl(ent.x, i + 2 + half); float n1 = __shfl(__int_as_float(ent.y), i + 2 + half);
            unsigned v0 = tab32[(size_t)((unsigned)s0 << 5) + lpos];
            unsigned v1 = tab32[(size_t)((unsigned)s1 << 5) + lpos];
            float f0 = n0 * AGG_SC, f1 = n1 * AGG_SC;
            a0x += __float2int_rz(f0 * bf2f((unsigned short)v0));
            a0y += __float2int_rz(f0 * bf2f((unsigned short)(v0 >> 16)));
            a1x += __float2int_rz(f1 * bf2f((unsigned short)v1));
            a1y += __float2int_rz(f1 * bf2f((unsigned short)(v1 >> 16)));
        }
        for (; i < m; ++i) {
            int   s0 = __shfl(ent.x, i); float n0 = __shfl(__int_as_float(ent.y), i);
            if (half) n0 = 0.f;         // half 0 covers all 64 features alone
            unsigned v0 = tab32[(size_t)((unsigned)s0 << 5) + lpos];
            float f0 = n0 * AGG_SC;
            a0x += __float2int_rz(f0 * bf2f((unsigned short)v0));
            a0y += __float2int_rz(f0 * bf2f((unsigned short)(v0 >> 16)));
        }
    }
    int ax = a0x + a1x, ay = a0y + a1y;
    ax += __shfl_xor(ax, 32);           // int add: order-invariant
    ay += __shfl_xor(ay, 32);
    return make_float2((float)ax * AGG_INV, (float)ay * AGG_INV);
}

// f32-accumulation variant for layer 2:
__device__ __forceinline__ float2 agg_row_pair_f(const int2* __restrict__ csr, int s, int epos,
                                                 const unsigned int* __restrict__ tab32, int lane) {
    float a0x = 0.f, a0y = 0.f, a1x = 0.f, a1y = 0.f;
    int half = lane >> 5, lpos = lane & 31;
    for (int base = s; base < epos; base += 64) {
        int m = epos - base; if (m > 64) m = 64;
        int2 ent = (lane < m) ? csr[base + lane] : make_int2(0, 0);
        int i = 0;
        for (; i + 4 <= m; i += 4) {
            int   s0 = __shfl(ent.x, i + half);     float n0 = __shfl(__int_as_float(ent.y), i + half);
            int   s1 = __shfl(ent.x, i + 2 + half); float n1 = __shfl(__int_as_float(ent.y), i + 2 + half);
            unsigned v0 = tab32[(size_t)((unsigned)s0 << 5) + lpos];
            unsigned v1 = tab32[(size_t)((unsigned)s1 << 5) + lpos];
            a0x += n0 * bf2f((unsigned short)v0);
            a0y += n0 * bf2f((unsigned short)(v0 >> 16));
            a1x += n1 * bf2f((unsigned short)v1);
            a1y += n1 * bf2f((unsigned short)(v1 >> 16));
        }
        for (; i < m; ++i) {
            int   s0 = __shfl(ent.x, i); float n0 = __shfl(__int_as_float(ent.y), i);
            if (half) n0 = 0.f;
            unsigned v0 = tab32[(size_t)((unsigned)s0 << 5) + lpos];
            a0x += n0 * bf2f((unsigned short)v0);
            a0y += n0 * bf2f((unsigned short)(v0 >> 16));
        }
    }
    float ax = a0x + a1x, ay = a0y + a1y;
    ax += __shfl_xor(ax, 32);
    ay += __shfl_xor(ay, 32);
    return make_float2(ax, ay);
}

// ---------- aggregation layer1: h1(bf16, deterministic) = relu(sum + b1) ----------
__global__ __launch_bounds__(256) void k_agg1(const int2* __restrict__ csr, const int* __restrict__ row_start,
                                              const unsigned int* __restrict__ h1lin32,
                                              const float* __restrict__ b1,
                                              unsigned int* __restrict__ h1_32, int N) {
    int wid = threadIdx.x >> 6, lane = threadIdx.x & 63;
    int node = blockIdx.x * 4 + wid;
    if (node >= N) return;
    float2 acc = agg_row_pair_fx(csr, row_start[node], row_start[node + 1], h1lin32, lane);
    if (lane < 32) {
        float2 bp = ((const float2*)b1)[lane];
        unsigned r = (unsigned)f2bf(fmaxf(acc.x + bp.x, 0.f))
                   | ((unsigned)f2bf(fmaxf(acc.y + bp.y, 0.f)) << 16);
        h1_32[(size_t)node * 32 + lane] = r;
    }
}

// ---------- fused agg2 + GEMM2 (no LDS): out = relu((sum norm*h1[src]) @ W2^T + b2) ----------
__global__ __launch_bounds__(256) void k_agg2f(const int2* __restrict__ csr, const int* __restrict__ row_start,
                                               const unsigned int* __restrict__ h1_32,
                                               const float* __restrict__ W2t,
                                               const float* __restrict__ b2, float* __restrict__ out, int N) {
    int wid = threadIdx.x >> 6, lane = threadIdx.x & 63;
    int node = blockIdx.x * 4 + wid;
    if (node >= N) return;
    float2 acc = agg_row_pair_f(csr, row_start[node], row_start[node + 1], h1_32, lane);
    // epilogue: out[node][j] = relu(sum_f acc_f * W2[j][f] + b2[j]), j = lane, lane+64
    float o0 = b2[lane], o1 = b2[lane + 64];
    #pragma unroll 4
    for (int p = 0; p < 32; ++p) {
        float ae = __shfl(acc.x, p);    // feature 2p   (uniform -> readlane)
        float ao = __shfl(acc.y, p);    // feature 2p+1
        o0 += ae * W2t[(2 * p) * FIN + lane]      + ao * W2t[(2 * p + 1) * FIN + lane];
        o1 += ae * W2t[(2 * p) * FIN + 64 + lane] + ao * W2t[(2 * p + 1) * FIN + 64 + lane];
    }
    out[(size_t)node * FIN + lane] = fmaxf(o0, 0.f);
    out[(size_t)node * FIN + 64 + lane] = fmaxf(o1, 0.f);
}

extern "C" void kernel_launch(void* const* d_in, const int* in_sizes, int n_in,
                              void* d_out, int out_size, void* d_ws, size_t ws_size,
                              hipStream_t stream) {
    const float* x  = (const float*)d_in[0];
    const void*  ei = d_in[1];
    const float* w  = (const float*)d_in[2];
    const float* W1 = (const float*)d_in[3];
    const float* b1 = (const float*)d_in[4];
    const float* W2 = (const float*)d_in[5];
    const float* b2 = (const float*)d_in[6];
    float* out = (float*)d_out;
    int N = in_sizes[0] / FIN;
    int E = in_sizes[2];

    char* ws = (char*)d_ws;
    size_t off = 0;
    auto alloc = [&](size_t b) { size_t o = off; off = (off + b + 255) & ~255ULL; return o; };
    int*   flag      = (int*)(ws + alloc(4));
    unsigned int* packed = (unsigned int*)(ws + alloc((size_t)N * 4));
    float* dis       = (float*)(ws + alloc((size_t)N * 4));
    int*   row_start = (int*)(ws + alloc((size_t)(N + 1) * 4));
    int*   partial   = (int*)(ws + alloc(4096));
    float* W2t       = (float*)(ws + alloc((size_t)FIN * FHID * 4));
    int2*  csr       = (int2*)(ws + alloc((size_t)E * 8));
    unsigned int* h1_32    = (unsigned int*)(ws + alloc((size_t)N * FHID * 2));
    unsigned int* h1lin32  = (unsigned int*)(ws + alloc((size_t)N * FHID * 2));
    unsigned char* rank = (unsigned char*)h1lin32;  // alias: rank (E bytes <= N*128B) dead before k_gemm1 writes h1lin

    hipMemsetAsync(packed, 0, (size_t)N * 4, stream);

    k_detect<<<1, 64, 0, stream>>>((const uint32_t*)ei, flag);

    int eb = (E + 255) / 256;
    k_deg<<<eb, 256, 0, stream>>>(ei, w, packed, rank, flag, E);
    k_dis<<<(N + 255) / 256, 256, 0, stream>>>(packed, dis, N);

    int nparts = (N + CHUNK - 1) / CHUNK;
    k_scan_part<<<nparts, 256, 0, stream>>>(packed, partial, N);
    k_scan_top<<<1, 64, 0, stream>>>(partial, nparts, row_start, N);
    k_scan_chunk<<<nparts, 256, 0, stream>>>(packed, partial, row_start, N);

    k_fill<<<eb, 256, 0, stream>>>(ei, w, dis, row_start, rank, csr, flag, E);
    k_w2t<<<(FIN * FHID + 255) / 256, 256, 0, stream>>>(W2, W2t);

    k_gemm1<<<(N + 31) / 32, 256, 0, stream>>>(x, W1, (unsigned short*)h1lin32, N);
    k_agg1<<<(N + 3) / 4, 256, 0, stream>>>(csr, row_start, h1lin32, b1, h1_32, N);
    k_agg2f<<<(N + 3) / 4, 256, 0, stream>>>(csr, row_start, h1_32, W2t, b2, out, N);
}

// Round 11
// 993.969 us; speedup vs baseline: 1.2546x; 1.0159x over previous
//
#include <hip/hip_runtime.h>
#include <stdint.h>

// x[N,128] f32, edge_index[2,E] int32/64, ew[E] f32, W1[64,128], b1[64], W2[128,64], b2[128]
#define FIN 128
#define FHID 64
#define CHUNK 2048
#define FIX_SCALE 65536.0f      // 2^16 fixed point for weighted degree
#define FIX_INV   (1.0f / 65536.0f)
#define AGG_SC    262144.0f     // 2^18 fixed point for order-invariant agg1
#define AGG_INV   (1.0f / 262144.0f)

__device__ __forceinline__ float bf2f(unsigned short u) {
    union { unsigned int i; float f; } v; v.i = ((unsigned int)u) << 16; return v.f;
}
__device__ __forceinline__ unsigned short f2bf(float f) {
    union { float f; unsigned int i; } v; v.f = f;
    unsigned int u = v.i;
    u += 0x7FFFu + ((u >> 16) & 1u);   // round-to-nearest-even
    return (unsigned short)(u >> 16);
}

// ---------- dtype detection: int64 edge_index has odd 32-bit words == 0 ----------
__global__ void k_detect(const uint32_t* __restrict__ ei, int* __restrict__ flag) {
    if (blockIdx.x == 0 && threadIdx.x == 0) {
        uint32_t o = 0;
        #pragma unroll
        for (int i = 1; i < 16; i += 2) o |= ei[i];
        *flag = (o == 0) ? 1 : 0;
    }
}

__device__ __forceinline__ int edge_at(const void* ei, long long idx, int is64) {
    if (is64) return (int)((const long long*)ei)[idx];
    return ((const int*)ei)[idx];
}

// ---------- packed degree + per-edge rank: one u32 atomic per edge ----------
__global__ __launch_bounds__(256) void k_deg(const void* __restrict__ ei, const float* __restrict__ w,
                                             unsigned int* __restrict__ packed,
                                             unsigned char* __restrict__ rank,
                                             const int* __restrict__ flag, int E) {
    int e = blockIdx.x * 256 + threadIdx.x;
    if (e >= E) return;
    int is64 = *flag;
    int c = edge_at(ei, (long long)E + e, is64);
    unsigned int inc = (1u << 24) | __float2uint_rn(w[e] * FIX_SCALE);
    unsigned int old = atomicAdd(&packed[c], inc);
    rank[e] = (unsigned char)(old >> 24);
}

// ---------- packed -> deg^-1/2 ----------
__global__ __launch_bounds__(256) void k_dis(const unsigned int* __restrict__ packed,
                                             float* __restrict__ dis, int N) {
    int i = blockIdx.x * 256 + threadIdx.x;
    if (i < N) {
        float d = (float)(packed[i] & 0xFFFFFFu) * FIX_INV;
        dis[i] = (d > 0.f) ? rsqrtf(d) : 0.f;
    }
}

// ---------- exclusive scan of packed counts -> row_start ----------
__global__ __launch_bounds__(256) void k_scan_part(const unsigned int* __restrict__ packed,
                                                   int* __restrict__ partial, int N) {
    __shared__ int sdata[256];
    int b = blockIdx.x, t = threadIdx.x;
    int base = b * CHUNK;
    int sum = 0;
    #pragma unroll
    for (int q = 0; q < CHUNK / 256; ++q) {
        int idx = base + q * 256 + t;
        if (idx < N) sum += (int)(packed[idx] >> 24);
    }
    sdata[t] = sum; __syncthreads();
    for (int off = 128; off > 0; off >>= 1) {
        if (t < off) sdata[t] += sdata[t + off];
        __syncthreads();
    }
    if (t == 0) partial[b] = sdata[0];
}

__global__ void k_scan_top(int* partial, int nparts, int* row_start, int N) {
    if (blockIdx.x == 0 && threadIdx.x == 0) {
        int run = 0;
        for (int i = 0; i < nparts; ++i) { int v = partial[i]; partial[i] = run; run += v; }
        row_start[N] = run;   // == E
    }
}

__global__ __launch_bounds__(256) void k_scan_chunk(const unsigned int* __restrict__ packed,
                                                    const int* __restrict__ partial,
                                                    int* __restrict__ row_start, int N) {
    __shared__ int tsum[256];
    __shared__ int toff[256];
    int b = blockIdx.x, t = threadIdx.x;
    int base = b * CHUNK + t * 8;
    int v[8]; int s = 0;
    #pragma unroll
    for (int q = 0; q < 8; ++q) {
        int idx = base + q;
        v[q] = (idx < N) ? (int)(packed[idx] >> 24) : 0;
        s += v[q];
    }
    tsum[t] = s; __syncthreads();
    if (t == 0) {
        int run = partial[b];
        for (int i = 0; i < 256; ++i) { int x = tsum[i]; toff[i] = run; run += x; }
    }
    __syncthreads();
    int ex = toff[t];
    #pragma unroll
    for (int q = 0; q < 8; ++q) {
        int idx = base + q;
        if (idx < N) row_start[idx] = ex;
        ex += v[q];
    }
}

// ---------- CSR fill (atomic-free): csr[row_start[c]+rank[e]] = {src, norm} ----------
__global__ __launch_bounds__(256) void k_fill(const void* __restrict__ ei, const float* __restrict__ w,
                                              const float* __restrict__ dis,
                                              const int* __restrict__ row_start,
                                              const unsigned char* __restrict__ rank,
                                              int2* __restrict__ csr,
                                              const int* __restrict__ flag, int E) {
    int e = blockIdx.x * 256 + threadIdx.x;
    if (e >= E) return;
    int is64 = *flag;
    int r = edge_at(ei, e, is64);
    int c = edge_at(ei, (long long)E + e, is64);
    float nm = dis[r] * w[e] * dis[c];
    int pos = row_start[c] + (int)rank[e];
    csr[pos] = make_int2(r, __float_as_int(nm));
}

// ---------- W2 transpose: W2t[k*128+j] = W2[j*64+k] ----------
__global__ __launch_bounds__(256) void k_w2t(const float* __restrict__ W2, float* __restrict__ W2t) {
    int i = blockIdx.x * 256 + threadIdx.x;   // 8192 elements
    if (i < FIN * FHID) {
        int j = i >> 6, k = i & 63;
        W2t[k * FIN + j] = W2[i];
    }
}

// ---------- GEMM1: h1lin[N,64](bf16, deterministic) = x[N,128] @ W1^T ----------
__global__ __launch_bounds__(256, 4) void k_gemm1(const float* __restrict__ x, const float* __restrict__ W1,
                                                  unsigned short* __restrict__ h1lin, int N) {
    __shared__ float Wt[FIN * 65];      // Wt[k*65+j] = W1[j*128+k], padded: conflict-free
    __shared__ float xt[32 * FIN];      // 16 KB
    int t = threadIdx.x;
    for (int i = t; i < FHID * FIN; i += 256) {
        int j = i >> 7, k = i & 127;
        Wt[k * 65 + j] = W1[i];         // lane-varying k -> stride 65 -> conflict-free
    }
    int r0 = blockIdx.x * 32;
    const float4* xg = (const float4*)(x + (size_t)r0 * FIN);
    float4* xt4 = (float4*)xt;
    #pragma unroll
    for (int q = 0; q < 4; ++q) {
        int i = t + q * 256;            // 1024 float4 total, 32 per row
        if (r0 + (i >> 5) < N) xt4[i] = xg[i];
    }
    __syncthreads();
    int j = t & 63, rg = t >> 6;        // rg uniform per wave
    float acc[8];
    #pragma unroll
    for (int r = 0; r < 8; ++r) acc[r] = 0.f;
    for (int kk = 0; kk < FIN; kk += 4) {
        float w0 = Wt[(kk + 0) * 65 + j];
        float w1 = Wt[(kk + 1) * 65 + j];
        float w2 = Wt[(kk + 2) * 65 + j];
        float w3 = Wt[(kk + 3) * 65 + j];
        #pragma unroll
        for (int r = 0; r < 8; ++r) {
            float4 xv = xt4[(rg * 8 + r) * 32 + (kk >> 2)];
            acc[r] += xv.x * w0 + xv.y * w1 + xv.z * w2 + xv.w * w3;
        }
    }
    #pragma unroll
    for (int r = 0; r < 8; ++r) {
        int row = r0 + rg * 8 + r;
        if (row < N) h1lin[(size_t)row * FHID + j] = f2bf(acc[r]);
    }
}

// ---------- dual-node interleaved pair-gather aggregation ----------
// Each wave owns nodes A=2k, B=2k+1 with independent chains -> 2x outstanding
// gathers. Pair scheme per node: lanes 0-31 edge i, lanes 32-63 edge i+1;
// lane holds features (2*lpos, 2*lpos+1) as u32 = 2 bf16.
// mA/mB/i are wave-uniform -> branches are scalar, no divergence.

// Fixed-point (order-invariant) variant for layer 1:
__global__ __launch_bounds__(256) void k_agg1(const int2* __restrict__ csr, const int* __restrict__ row_start,
                                              const unsigned int* __restrict__ tab32,
                                              const float* __restrict__ b1,
                                              unsigned int* __restrict__ h1_32, int N) {
    int wid = threadIdx.x >> 6, lane = threadIdx.x & 63;
    int nodeA = blockIdx.x * 8 + wid * 2;
    if (nodeA >= N) return;
    int nodeB = nodeA + 1;
    bool hasB = nodeB < N;
    int half = lane >> 5, lpos = lane & 31;
    int baseA = row_start[nodeA], eA = row_start[nodeA + 1];
    int baseB = hasB ? eA : 0, eB = hasB ? row_start[nodeB + 1] : 0;
    int aAx0 = 0, aAy0 = 0, aAx1 = 0, aAy1 = 0;
    int aBx0 = 0, aBy0 = 0, aBx1 = 0, aBy1 = 0;
    while (baseA < eA || baseB < eB) {
        int mA = eA - baseA; mA = mA < 0 ? 0 : (mA > 64 ? 64 : mA);
        int mB = eB - baseB; mB = mB < 0 ? 0 : (mB > 64 ? 64 : mB);
        int2 entA = (lane < mA) ? csr[baseA + lane] : make_int2(0, 0);
        int2 entB = (lane < mB) ? csr[baseB + lane] : make_int2(0, 0);
        int mMax = mA > mB ? mA : mB;
        int i = 0;
        for (; i + 4 <= mMax; i += 4) {
            if (i < mA) {
                int s0 = __shfl(entA.x, i + half);     float n0 = __shfl(__int_as_float(entA.y), i + half);
                int s1 = __shfl(entA.x, i + 2 + half); float n1 = __shfl(__int_as_float(entA.y), i + 2 + half);
                unsigned v0 = tab32[(size_t)((unsigned)s0 << 5) + lpos];
                unsigned v1 = tab32[(size_t)((unsigned)s1 << 5) + lpos];
                float f0 = n0 * AGG_SC, f1 = n1 * AGG_SC;
                aAx0 += __float2int_rz(f0 * bf2f((unsigned short)v0));
                aAy0 += __float2int_rz(f0 * bf2f((unsigned short)(v0 >> 16)));
                aAx1 += __float2int_rz(f1 * bf2f((unsigned short)v1));
                aAy1 += __float2int_rz(f1 * bf2f((unsigned short)(v1 >> 16)));
            }
            if (i < mB) {
                int s0 = __shfl(entB.x, i + half);     float n0 = __shfl(__int_as_float(entB.y), i + half);
                int s1 = __shfl(entB.x, i + 2 + half); float n1 = __shfl(__int_as_float(entB.y), i + 2 + half);
                unsigned v0 = tab32[(size_t)((unsigned)s0 << 5) + lpos];
                unsigned v1 = tab32[(size_t)((unsigned)s1 << 5) + lpos];
                float f0 = n0 * AGG_SC, f1 = n1 * AGG_SC;
                aBx0 += __float2int_rz(f0 * bf2f((unsigned short)v0));
                aBy0 += __float2int_rz(f0 * bf2f((unsigned short)(v0 >> 16)));
                aBx1 += __float2int_rz(f1 * bf2f((unsigned short)v1));
                aBy1 += __float2int_rz(f1 * bf2f((unsigned short)(v1 >> 16)));
            }
        }
        for (; i < mMax; ++i) {
            if (i < mA) {
                int s0 = __shfl(entA.x, i); float n0 = __shfl(__int_as_float(entA.y), i);
                if (half) n0 = 0.f;
                unsigned v0 = tab32[(size_t)((unsigned)s0 << 5) + lpos];
                float f0 = n0 * AGG_SC;
                aAx0 += __float2int_rz(f0 * bf2f((unsigned short)v0));
                aAy0 += __float2int_rz(f0 * bf2f((unsigned short)(v0 >> 16)));
            }
            if (i < mB) {
                int s0 = __shfl(entB.x, i); float n0 = __shfl(__int_as_float(entB.y), i);
                if (half) n0 = 0.f;
                unsigned v0 = tab32[(size_t)((unsigned)s0 << 5) + lpos];
                float f0 = n0 * AGG_SC;
                aBx0 += __float2int_rz(f0 * bf2f((unsigned short)v0));
                aBy0 += __float2int_rz(f0 * bf2f((unsigned short)(v0 >> 16)));
            }
        }
        baseA += 64; baseB += 64;
    }
    int axA = aAx0 + aAx1, ayA = aAy0 + aAy1;
    axA += __shfl_xor(axA, 32); ayA += __shfl_xor(ayA, 32);   // int: order-invariant
    int axB = aBx0 + aBx1, ayB = aBy0 + aBy1;
    axB += __shfl_xor(axB, 32); ayB += __shfl_xor(ayB, 32);
    if (lane < 32) {
        float2 bp = ((const float2*)b1)[lane];
        unsigned rA = (unsigned)f2bf(fmaxf((float)axA * AGG_INV + bp.x, 0.f))
                    | ((unsigned)f2bf(fmaxf((float)ayA * AGG_INV + bp.y, 0.f)) << 16);
        h1_32[(size_t)nodeA * 32 + lane] = rA;
        if (hasB) {
            unsigned rB = (unsigned)f2bf(fmaxf((float)axB * AGG_INV + bp.x, 0.f))
                        | ((unsigned)f2bf(fmaxf((float)ayB * AGG_INV + bp.y, 0.f)) << 16);
            h1_32[(size_t)nodeB * 32 + lane] = rB;
        }
    }
}

// f32-accumulation variant fused with GEMM2 epilogue:
__global__ __launch_bounds__(256) void k_agg2f(const int2* __restrict__ csr, const int* __restrict__ row_start,
                                               const unsigned int* __restrict__ tab32,
                                               const float* __restrict__ W2t,
                                               const float* __restrict__ b2, float* __restrict__ out, int N) {
    int wid = threadIdx.x >> 6, lane = threadIdx.x & 63;
    int nodeA = blockIdx.x * 8 + wid * 2;
    if (nodeA >= N) return;
    int nodeB = nodeA + 1;
    bool hasB = nodeB < N;
    int half = lane >> 5, lpos = lane & 31;
    int baseA = row_start[nodeA], eA = row_start[nodeA + 1];
    int baseB = hasB ? eA : 0, eB = hasB ? row_start[nodeB + 1] : 0;
    float aAx0 = 0.f, aAy0 = 0.f, aAx1 = 0.f, aAy1 = 0.f;
    float aBx0 = 0.f, aBy0 = 0.f, aBx1 = 0.f, aBy1 = 0.f;
    while (baseA < eA || baseB < eB) {
        int mA = eA - baseA; mA = mA < 0 ? 0 : (mA > 64 ? 64 : mA);
        int mB = eB - baseB; mB = mB < 0 ? 0 : (mB > 64 ? 64 : mB);
        int2 entA = (lane < mA) ? csr[baseA + lane] : make_int2(0, 0);
        int2 entB = (lane < mB) ? csr[baseB + lane] : make_int2(0, 0);
        int mMax = mA > mB ? mA : mB;
        int i = 0;
        for (; i + 4 <= mMax; i += 4) {
            if (i < mA) {
                int s0 = __shfl(entA.x, i + half);     float n0 = __shfl(__int_as_float(entA.y), i + half);
                int s1 = __shfl(entA.x, i + 2 + half); float n1 = __shfl(__int_as_float(entA.y), i + 2 + half);
                unsigned v0 = tab32[(size_t)((unsigned)s0 << 5) + lpos];
                unsigned v1 = tab32[(size_t)((unsigned)s1 << 5) + lpos];
                aAx0 += n0 * bf2f((unsigned short)v0);
                aAy0 += n0 * bf2f((unsigned short)(v0 >> 16));
                aAx1 += n1 * bf2f((unsigned short)v1);
                aAy1 += n1 * bf2f((unsigned short)(v1 >> 16));
            }
            if (i < mB) {
                int s0 = __shfl(entB.x, i + half);     float n0 = __shfl(__int_as_float(entB.y), i + half);
                int s1 = __shfl(entB.x, i + 2 + half); float n1 = __shfl(__int_as_float(entB.y), i + 2 + half);
                unsigned v0 = tab32[(size_t)((unsigned)s0 << 5) + lpos];
                unsigned v1 = tab32[(size_t)((unsigned)s1 << 5) + lpos];
                aBx0 += n0 * bf2f((unsigned short)v0);
                aBy0 += n0 * bf2f((unsigned short)(v0 >> 16));
                aBx1 += n1 * bf2f((unsigned short)v1);
                aBy1 += n1 * bf2f((unsigned short)(v1 >> 16));
            }
        }
        for (; i < mMax; ++i) {
            if (i < mA) {
                int s0 = __shfl(entA.x, i); float n0 = __shfl(__int_as_float(entA.y), i);
                if (half) n0 = 0.f;
                unsigned v0 = tab32[(size_t)((unsigned)s0 << 5) + lpos];
                aAx0 += n0 * bf2f((unsigned short)v0);
                aAy0 += n0 * bf2f((unsigned short)(v0 >> 16));
            }
            if (i < mB) {
                int s0 = __shfl(entB.x, i); float n0 = __shfl(__int_as_float(entB.y), i);
                if (half) n0 = 0.f;
                unsigned v0 = tab32[(size_t)((unsigned)s0 << 5) + lpos];
                aBx0 += n0 * bf2f((unsigned short)v0);
                aBy0 += n0 * bf2f((unsigned short)(v0 >> 16));
            }
        }
        baseA += 64; baseB += 64;
    }
    float axA = aAx0 + aAx1, ayA = aAy0 + aAy1;
    axA += __shfl_xor(axA, 32); ayA += __shfl_xor(ayA, 32);
    float axB = aBx0 + aBx1, ayB = aBy0 + aBy1;
    axB += __shfl_xor(axB, 32); ayB += __shfl_xor(ayB, 32);
    // epilogue A: out[nodeA][j] = relu(sum_f acc_f * W2[j][f] + b2[j])
    {
        float o0 = b2[lane], o1 = b2[lane + 64];
        #pragma unroll 4
        for (int p = 0; p < 32; ++p) {
            float ae = __shfl(axA, p);
            float ao = __shfl(ayA, p);
            o0 += ae * W2t[(2 * p) * FIN + lane]      + ao * W2t[(2 * p + 1) * FIN + lane];
            o1 += ae * W2t[(2 * p) * FIN + 64 + lane] + ao * W2t[(2 * p + 1) * FIN + 64 + lane];
        }
        out[(size_t)nodeA * FIN + lane] = fmaxf(o0, 0.f);
        out[(size_t)nodeA * FIN + 64 + lane] = fmaxf(o1, 0.f);
    }
    if (hasB) {
        float o0 = b2[lane], o1 = b2[lane + 64];
        #pragma unroll 4
        for (int p = 0; p < 32; ++p) {
            float ae = __shfl(axB, p);
            float ao = __shfl(ayB, p);
            o0 += ae * W2t[(2 * p) * FIN + lane]      + ao * W2t[(2 * p + 1) * FIN + lane];
            o1 += ae * W2t[(2 * p) * FIN + 64 + lane] + ao * W2t[(2 * p + 1) * FIN + 64 + lane];
        }
        out[(size_t)nodeB * FIN + lane] = fmaxf(o0, 0.f);
        out[(size_t)nodeB * FIN + 64 + lane] = fmaxf(o1, 0.f);
    }
}

extern "C" void kernel_launch(void* const* d_in, const int* in_sizes, int n_in,
                              void* d_out, int out_size, void* d_ws, size_t ws_size,
                              hipStream_t stream) {
    const float* x  = (const float*)d_in[0];
    const void*  ei = d_in[1];
    const float* w  = (const float*)d_in[2];
    const float* W1 = (const float*)d_in[3];
    const float* b1 = (const float*)d_in[4];
    const float* W2 = (const float*)d_in[5];
    const float* b2 = (const float*)d_in[6];
    float* out = (float*)d_out;
    int N = in_sizes[0] / FIN;
    int E = in_sizes[2];

    char* ws = (char*)d_ws;
    size_t off = 0;
    auto alloc = [&](size_t b) { size_t o = off; off = (off + b + 255) & ~255ULL; return o; };
    int*   flag      = (int*)(ws + alloc(4));
    unsigned int* packed = (unsigned int*)(ws + alloc((size_t)N * 4));
    float* dis       = (float*)(ws + alloc((size_t)N * 4));
    int*   row_start = (int*)(ws + alloc((size_t)(N + 1) * 4));
    int*   partial   = (int*)(ws + alloc(4096));
    float* W2t       = (float*)(ws + alloc((size_t)FIN * FHID * 4));
    int2*  csr       = (int2*)(ws + alloc((size_t)E * 8));
    unsigned int* h1_32    = (unsigned int*)(ws + alloc((size_t)N * FHID * 2));
    unsigned int* h1lin32  = (unsigned int*)(ws + alloc((size_t)N * FHID * 2));
    unsigned char* rank = (unsigned char*)h1lin32;  // alias: rank (E bytes <= N*128B) dead before k_gemm1 writes h1lin

    hipMemsetAsync(packed, 0, (size_t)N * 4, stream);

    k_detect<<<1, 64, 0, stream>>>((const uint32_t*)ei, flag);

    int eb = (E + 255) / 256;
    k_deg<<<eb, 256, 0, stream>>>(ei, w, packed, rank, flag, E);
    k_dis<<<(N + 255) / 256, 256, 0, stream>>>(packed, dis, N);

    int nparts = (N + CHUNK - 1) / CHUNK;
    k_scan_part<<<nparts, 256, 0, stream>>>(packed, partial, N);
    k_scan_top<<<1, 64, 0, stream>>>(partial, nparts, row_start, N);
    k_scan_chunk<<<nparts, 256, 0, stream>>>(packed, partial, row_start, N);

    k_fill<<<eb, 256, 0, stream>>>(ei, w, dis, row_start, rank, csr, flag, E);
    k_w2t<<<(FIN * FHID + 255) / 256, 256, 0, stream>>>(W2, W2t);

    k_gemm1<<<(N + 31) / 32, 256, 0, stream>>>(x, W1, (unsigned short*)h1lin32, N);
    k_agg1<<<(N + 7) / 8, 256, 0, stream>>>(csr, row_start, h1lin32, b1, h1_32, N);
    k_agg2f<<<(N + 7) / 8, 256, 0, stream>>>(csr, row_start, h1_32, W2t, b2, out, N);
}

// Round 12
// 984.485 us; speedup vs baseline: 1.2667x; 1.0096x over previous
//
#include <hip/hip_runtime.h>
#include <stdint.h>

// x[N,128] f32, edge_index[2,E] int32/64, ew[E] f32, W1[64,128], b1[64], W2[128,64], b2[128]
#define FIN 128
#define FHID 64
#define CHUNK 2048
#define FIX_SCALE 65536.0f      // 2^16 fixed point for weighted degree
#define FIX_INV   (1.0f / 65536.0f)
#define AGG_SC    262144.0f     // 2^18 fixed point for order-invariant aggregation
#define AGG_INV   (1.0f / 262144.0f)

__device__ __forceinline__ float bf2f(unsigned short u) {
    union { unsigned int i; float f; } v; v.i = ((unsigned int)u) << 16; return v.f;
}
__device__ __forceinline__ unsigned short f2bf(float f) {
    union { float f; unsigned int i; } v; v.f = f;
    unsigned int u = v.i;
    u += 0x7FFFu + ((u >> 16) & 1u);   // round-to-nearest-even
    return (unsigned short)(u >> 16);
}

// ---------- dtype detection: int64 edge_index has odd 32-bit words == 0 ----------
__global__ void k_detect(const uint32_t* __restrict__ ei, int* __restrict__ flag) {
    if (blockIdx.x == 0 && threadIdx.x == 0) {
        uint32_t o = 0;
        #pragma unroll
        for (int i = 1; i < 16; i += 2) o |= ei[i];
        *flag = (o == 0) ? 1 : 0;
    }
}

__device__ __forceinline__ int edge_at(const void* ei, long long idx, int is64) {
    if (is64) return (int)((const long long*)ei)[idx];
    return ((const int*)ei)[idx];
}

// ---------- packed degree + per-edge rank: one u32 atomic per edge ----------
__global__ __launch_bounds__(256) void k_deg(const void* __restrict__ ei, const float* __restrict__ w,
                                             unsigned int* __restrict__ packed,
                                             unsigned char* __restrict__ rank,
                                             const int* __restrict__ flag, int E) {
    int e = blockIdx.x * 256 + threadIdx.x;
    if (e >= E) return;
    int is64 = *flag;
    int c = edge_at(ei, (long long)E + e, is64);
    unsigned int inc = (1u << 24) | __float2uint_rn(w[e] * FIX_SCALE);
    unsigned int old = atomicAdd(&packed[c], inc);
    rank[e] = (unsigned char)(old >> 24);
}

// ---------- packed -> deg^-1/2 ----------
__global__ __launch_bounds__(256) void k_dis(const unsigned int* __restrict__ packed,
                                             float* __restrict__ dis, int N) {
    int i = blockIdx.x * 256 + threadIdx.x;
    if (i < N) {
        float d = (float)(packed[i] & 0xFFFFFFu) * FIX_INV;
        dis[i] = (d > 0.f) ? rsqrtf(d) : 0.f;
    }
}

// ---------- exclusive scan of packed counts -> row_start ----------
__global__ __launch_bounds__(256) void k_scan_part(const unsigned int* __restrict__ packed,
                                                   int* __restrict__ partial, int N) {
    __shared__ int sdata[256];
    int b = blockIdx.x, t = threadIdx.x;
    int base = b * CHUNK;
    int sum = 0;
    #pragma unroll
    for (int q = 0; q < CHUNK / 256; ++q) {
        int idx = base + q * 256 + t;
        if (idx < N) sum += (int)(packed[idx] >> 24);
    }
    sdata[t] = sum; __syncthreads();
    for (int off = 128; off > 0; off >>= 1) {
        if (t < off) sdata[t] += sdata[t + off];
        __syncthreads();
    }
    if (t == 0) partial[b] = sdata[0];
}

__global__ void k_scan_top(int* partial, int nparts, int* row_start, int N) {
    if (blockIdx.x == 0 && threadIdx.x == 0) {
        int run = 0;
        for (int i = 0; i < nparts; ++i) { int v = partial[i]; partial[i] = run; run += v; }
        row_start[N] = run;   // == E
    }
}

__global__ __launch_bounds__(256) void k_scan_chunk(const unsigned int* __restrict__ packed,
                                                    const int* __restrict__ partial,
                                                    int* __restrict__ row_start, int N) {
    __shared__ int tsum[256];
    __shared__ int toff[256];
    int b = blockIdx.x, t = threadIdx.x;
    int base = b * CHUNK + t * 8;
    int v[8]; int s = 0;
    #pragma unroll
    for (int q = 0; q < 8; ++q) {
        int idx = base + q;
        v[q] = (idx < N) ? (int)(packed[idx] >> 24) : 0;
        s += v[q];
    }
    tsum[t] = s; __syncthreads();
    if (t == 0) {
        int run = partial[b];
        for (int i = 0; i < 256; ++i) { int x = tsum[i]; toff[i] = run; run += x; }
    }
    __syncthreads();
    int ex = toff[t];
    #pragma unroll
    for (int q = 0; q < 8; ++q) {
        int idx = base + q;
        if (idx < N) row_start[idx] = ex;
        ex += v[q];
    }
}

// ---------- CSR fill (atomic-free): csr[row_start[c]+rank[e]] = {src, norm} ----------
__global__ __launch_bounds__(256) void k_fill(const void* __restrict__ ei, const float* __restrict__ w,
                                              const float* __restrict__ dis,
                                              const int* __restrict__ row_start,
                                              const unsigned char* __restrict__ rank,
                                              int2* __restrict__ csr,
                                              const int* __restrict__ flag, int E) {
    int e = blockIdx.x * 256 + threadIdx.x;
    if (e >= E) return;
    int is64 = *flag;
    int r = edge_at(ei, e, is64);
    int c = edge_at(ei, (long long)E + e, is64);
    float nm = dis[r] * w[e] * dis[c];
    int pos = row_start[c] + (int)rank[e];
    csr[pos] = make_int2(r, __float_as_int(nm));
}

// ---------- GEMM1: h1lin[N,64](bf16, deterministic) = x[N,128] @ W1^T ----------
__global__ __launch_bounds__(256, 4) void k_gemm1(const float* __restrict__ x, const float* __restrict__ W1,
                                                  unsigned short* __restrict__ h1lin, int N) {
    __shared__ float Wt[FIN * 65];      // Wt[k*65+j] = W1[j*128+k], padded: conflict-free
    __shared__ float xt[32 * FIN];      // 16 KB
    int t = threadIdx.x;
    for (int i = t; i < FHID * FIN; i += 256) {
        int j = i >> 7, k = i & 127;
        Wt[k * 65 + j] = W1[i];         // lane-varying k -> stride 65 -> conflict-free
    }
    int r0 = blockIdx.x * 32;
    const float4* xg = (const float4*)(x + (size_t)r0 * FIN);
    float4* xt4 = (float4*)xt;
    #pragma unroll
    for (int q = 0; q < 4; ++q) {
        int i = t + q * 256;            // 1024 float4 total, 32 per row
        if (r0 + (i >> 5) < N) xt4[i] = xg[i];
    }
    __syncthreads();
    int j = t & 63, rg = t >> 6;        // rg uniform per wave
    float acc[8];
    #pragma unroll
    for (int r = 0; r < 8; ++r) acc[r] = 0.f;
    for (int kk = 0; kk < FIN; kk += 4) {
        float w0 = Wt[(kk + 0) * 65 + j];
        float w1 = Wt[(kk + 1) * 65 + j];
        float w2 = Wt[(kk + 2) * 65 + j];
        float w3 = Wt[(kk + 3) * 65 + j];
        #pragma unroll
        for (int r = 0; r < 8; ++r) {
            float4 xv = xt4[(rg * 8 + r) * 32 + (kk >> 2)];
            acc[r] += xv.x * w0 + xv.y * w1 + xv.z * w2 + xv.w * w3;
        }
    }
    #pragma unroll
    for (int r = 0; r < 8; ++r) {
        int row = r0 + rg * 8 + r;
        if (row < N) h1lin[(size_t)row * FHID + j] = f2bf(acc[r]);
    }
}

// ---------- dual-node interleaved pair-gather aggregation (int-fx, order-invariant) ----------
// Each wave owns nodes A=2k, B=2k+1. lanes 0-31 edge i, lanes 32-63 edge i+1;
// lane holds features (2*lpos, 2*lpos+1) as u32 = 2 bf16. Int chains + int
// cross-half merge -> result is bit-identical under any CSR row permutation.
// OUT_MODE 0: h1 = relu(acc + b1) (layer 1); OUT_MODE 1: aggv = acc (layer 2 pre-GEMM)
template <int OUT_MODE>
__device__ __forceinline__ void agg_fx_dual(const int2* __restrict__ csr, const int* __restrict__ row_start,
                                            const unsigned int* __restrict__ tab32,
                                            const float* __restrict__ b1,
                                            unsigned int* __restrict__ out32, int N) {
    int wid = threadIdx.x >> 6, lane = threadIdx.x & 63;
    int nodeA = blockIdx.x * 8 + wid * 2;
    if (nodeA >= N) return;
    int nodeB = nodeA + 1;
    bool hasB = nodeB < N;
    int half = lane >> 5, lpos = lane & 31;
    int baseA = row_start[nodeA], eA = row_start[nodeA + 1];
    int baseB = hasB ? eA : 0, eB = hasB ? row_start[nodeB + 1] : 0;
    int aAx0 = 0, aAy0 = 0, aAx1 = 0, aAy1 = 0;
    int aBx0 = 0, aBy0 = 0, aBx1 = 0, aBy1 = 0;
    while (baseA < eA || baseB < eB) {
        int mA = eA - baseA; mA = mA < 0 ? 0 : (mA > 64 ? 64 : mA);
        int mB = eB - baseB; mB = mB < 0 ? 0 : (mB > 64 ? 64 : mB);
        int2 entA = (lane < mA) ? csr[baseA + lane] : make_int2(0, 0);
        int2 entB = (lane < mB) ? csr[baseB + lane] : make_int2(0, 0);
        int mMax = mA > mB ? mA : mB;
        int i = 0;
        for (; i + 4 <= mMax; i += 4) {
            if (i < mA) {
                int s0 = __shfl(entA.x, i + half);     float n0 = __shfl(__int_as_float(entA.y), i + half);
                int s1 = __shfl(entA.x, i + 2 + half); float n1 = __shfl(__int_as_float(entA.y), i + 2 + half);
                unsigned v0 = tab32[(size_t)((unsigned)s0 << 5) + lpos];
                unsigned v1 = tab32[(size_t)((unsigned)s1 << 5) + lpos];
                float f0 = n0 * AGG_SC, f1 = n1 * AGG_SC;
                aAx0 += __float2int_rz(f0 * bf2f((unsigned short)v0));
                aAy0 += __float2int_rz(f0 * bf2f((unsigned short)(v0 >> 16)));
                aAx1 += __float2int_rz(f1 * bf2f((unsigned short)v1));
                aAy1 += __float2int_rz(f1 * bf2f((unsigned short)(v1 >> 16)));
            }
            if (i < mB) {
                int s0 = __shfl(entB.x, i + half);     float n0 = __shfl(__int_as_float(entB.y), i + half);
                int s1 = __shfl(entB.x, i + 2 + half); float n1 = __shfl(__int_as_float(entB.y), i + 2 + half);
                unsigned v0 = tab32[(size_t)((unsigned)s0 << 5) + lpos];
                unsigned v1 = tab32[(size_t)((unsigned)s1 << 5) + lpos];
                float f0 = n0 * AGG_SC, f1 = n1 * AGG_SC;
                aBx0 += __float2int_rz(f0 * bf2f((unsigned short)v0));
                aBy0 += __float2int_rz(f0 * bf2f((unsigned short)(v0 >> 16)));
                aBx1 += __float2int_rz(f1 * bf2f((unsigned short)v1));
                aBy1 += __float2int_rz(f1 * bf2f((unsigned short)(v1 >> 16)));
            }
        }
        for (; i < mMax; ++i) {
            if (i < mA) {
                int s0 = __shfl(entA.x, i); float n0 = __shfl(__int_as_float(entA.y), i);
                if (half) n0 = 0.f;
                unsigned v0 = tab32[(size_t)((unsigned)s0 << 5) + lpos];
                float f0 = n0 * AGG_SC;
                aAx0 += __float2int_rz(f0 * bf2f((unsigned short)v0));
                aAy0 += __float2int_rz(f0 * bf2f((unsigned short)(v0 >> 16)));
            }
            if (i < mB) {
                int s0 = __shfl(entB.x, i); float n0 = __shfl(__int_as_float(entB.y), i);
                if (half) n0 = 0.f;
                unsigned v0 = tab32[(size_t)((unsigned)s0 << 5) + lpos];
                float f0 = n0 * AGG_SC;
                aBx0 += __float2int_rz(f0 * bf2f((unsigned short)v0));
                aBy0 += __float2int_rz(f0 * bf2f((unsigned short)(v0 >> 16)));
            }
        }
        baseA += 64; baseB += 64;
    }
    int axA = aAx0 + aAx1, ayA = aAy0 + aAy1;
    axA += __shfl_xor(axA, 32); ayA += __shfl_xor(ayA, 32);   // int: order-invariant
    int axB = aBx0 + aBx1, ayB = aBy0 + aBy1;
    axB += __shfl_xor(axB, 32); ayB += __shfl_xor(ayB, 32);
    if (lane < 32) {
        float fxA = (float)axA * AGG_INV, fyA = (float)ayA * AGG_INV;
        float fxB = (float)axB * AGG_INV, fyB = (float)ayB * AGG_INV;
        if (OUT_MODE == 0) {
            float2 bp = ((const float2*)b1)[lane];
            fxA = fmaxf(fxA + bp.x, 0.f); fyA = fmaxf(fyA + bp.y, 0.f);
            fxB = fmaxf(fxB + bp.x, 0.f); fyB = fmaxf(fyB + bp.y, 0.f);
        }
        out32[(size_t)nodeA * 32 + lane] = (unsigned)f2bf(fxA) | ((unsigned)f2bf(fyA) << 16);
        if (hasB)
            out32[(size_t)nodeB * 32 + lane] = (unsigned)f2bf(fxB) | ((unsigned)f2bf(fyB) << 16);
    }
}

__global__ __launch_bounds__(256) void k_agg1(const int2* __restrict__ csr, const int* __restrict__ row_start,
                                              const unsigned int* __restrict__ h1lin32,
                                              const float* __restrict__ b1,
                                              unsigned int* __restrict__ h1_32, int N) {
    agg_fx_dual<0>(csr, row_start, h1lin32, b1, h1_32, N);
}

__global__ __launch_bounds__(256) void k_agg2(const int2* __restrict__ csr, const int* __restrict__ row_start,
                                              const unsigned int* __restrict__ h1_32,
                                              unsigned int* __restrict__ aggv32, int N) {
    agg_fx_dual<1>(csr, row_start, h1_32, (const float*)nullptr, aggv32, N);
}

// ---------- GEMM2: out[N,128] = relu(aggv[N,64](bf16) @ W2[128,64]^T + b2) ----------
#define G2_ROWS 16
__global__ __launch_bounds__(256, 4) void k_gemm2(const unsigned int* __restrict__ aggv32,
                                                  const float* __restrict__ W2,
                                                  const float* __restrict__ b2,
                                                  float* __restrict__ out, int N) {
    __shared__ float Wt[FHID * 129];            // Wt[k*129+j] = W2[j*64+k]; 33 KB, conflict-free
    __shared__ unsigned int at[G2_ROWS * 33];   // at[r*33+c] = aggv32[r0+r][c]; 2.1 KB
    int t = threadIdx.x;
    for (int i = t; i < FIN * FHID; i += 256) {
        int j = i >> 6, k = i & 63;
        Wt[k * 129 + j] = W2[i];                // lane-varying k -> stride 129 -> conflict-free
    }
    int r0 = blockIdx.x * G2_ROWS;
    for (int i = t; i < G2_ROWS * 32; i += 256) {
        int r = i >> 5, c = i & 31;
        at[r * 33 + c] = (r0 + r < N) ? aggv32[(size_t)(r0 + r) * 32 + c] : 0u;
    }
    __syncthreads();
    int j = t & 127, rg = t >> 7;               // rg uniform per wave; rows rg*8..rg*8+7
    float acc[8];
    #pragma unroll
    for (int r = 0; r < 8; ++r) acc[r] = 0.f;
    for (int c = 0; c < 32; c += 2) {           // 4 k's per iteration
        float w0 = Wt[(2 * c + 0) * 129 + j];
        float w1 = Wt[(2 * c + 1) * 129 + j];
        float w2 = Wt[(2 * c + 2) * 129 + j];
        float w3 = Wt[(2 * c + 3) * 129 + j];
        #pragma unroll
        for (int r = 0; r < 8; ++r) {
            unsigned a01 = at[(rg * 8 + r) * 33 + c];       // broadcast
            unsigned a23 = at[(rg * 8 + r) * 33 + c + 1];
            acc[r] += bf2f((unsigned short)a01) * w0 + bf2f((unsigned short)(a01 >> 16)) * w1
                    + bf2f((unsigned short)a23) * w2 + bf2f((unsigned short)(a23 >> 16)) * w3;
        }
    }
    float bj = b2[j];
    #pragma unroll
    for (int r = 0; r < 8; ++r) {
        int row = r0 + rg * 8 + r;
        if (row < N) out[(size_t)row * FIN + j] = fmaxf(acc[r] + bj, 0.f);
    }
}

extern "C" void kernel_launch(void* const* d_in, const int* in_sizes, int n_in,
                              void* d_out, int out_size, void* d_ws, size_t ws_size,
                              hipStream_t stream) {
    const float* x  = (const float*)d_in[0];
    const void*  ei = d_in[1];
    const float* w  = (const float*)d_in[2];
    const float* W1 = (const float*)d_in[3];
    const float* b1 = (const float*)d_in[4];
    const float* W2 = (const float*)d_in[5];
    const float* b2 = (const float*)d_in[6];
    float* out = (float*)d_out;
    int N = in_sizes[0] / FIN;
    int E = in_sizes[2];

    char* ws = (char*)d_ws;
    size_t off = 0;
    auto alloc = [&](size_t b) { size_t o = off; off = (off + b + 255) & ~255ULL; return o; };
    int*   flag      = (int*)(ws + alloc(4));
    unsigned int* packed = (unsigned int*)(ws + alloc((size_t)N * 4));
    float* dis       = (float*)(ws + alloc((size_t)N * 4));
    int*   row_start = (int*)(ws + alloc((size_t)(N + 1) * 4));
    int*   partial   = (int*)(ws + alloc(4096));
    int2*  csr       = (int2*)(ws + alloc((size_t)E * 8));
    unsigned int* h1_32    = (unsigned int*)(ws + alloc((size_t)N * FHID * 2));
    unsigned int* aggv32   = (unsigned int*)(ws + alloc((size_t)N * FHID * 2));
    unsigned int* h1lin32  = (unsigned int*)(ws + alloc((size_t)N * FHID * 2));
    unsigned char* rank = (unsigned char*)h1lin32;  // alias: rank (E bytes <= N*128B) dead before k_gemm1 writes h1lin

    hipMemsetAsync(packed, 0, (size_t)N * 4, stream);

    k_detect<<<1, 64, 0, stream>>>((const uint32_t*)ei, flag);

    int eb = (E + 255) / 256;
    k_deg<<<eb, 256, 0, stream>>>(ei, w, packed, rank, flag, E);
    k_dis<<<(N + 255) / 256, 256, 0, stream>>>(packed, dis, N);

    int nparts = (N + CHUNK - 1) / CHUNK;
    k_scan_part<<<nparts, 256, 0, stream>>>(packed, partial, N);
    k_scan_top<<<1, 64, 0, stream>>>(partial, nparts, row_start, N);
    k_scan_chunk<<<nparts, 256, 0, stream>>>(packed, partial, row_start, N);

    k_fill<<<eb, 256, 0, stream>>>(ei, w, dis, row_start, rank, csr, flag, E);

    k_gemm1<<<(N + 31) / 32, 256, 0, stream>>>(x, W1, (unsigned short*)h1lin32, N);
    k_agg1<<<(N + 7) / 8, 256, 0, stream>>>(csr, row_start, h1lin32, b1, h1_32, N);
    k_agg2<<<(N + 7) / 8, 256, 0, stream>>>(csr, row_start, h1_32, aggv32, N);
    k_gemm2<<<(N + G2_ROWS - 1) / G2_ROWS, 256, 0, stream>>>(aggv32, W2, b2, out, N);
}

// Round 13
// 874.855 us; speedup vs baseline: 1.4254x; 1.1253x over previous
//
#include <hip/hip_runtime.h>
#include <stdint.h>

// x[N,128] f32, edge_index[2,E] int32/64, ew[E] f32, W1[64,128], b1[64], W2[128,64], b2[128]
#define FIN 128
#define FHID 64
#define CHUNK 2048
#define FIX_SCALE 65536.0f      // 2^16 fixed point for weighted degree
#define FIX_INV   (1.0f / 65536.0f)
#define AGG_SC    262144.0f     // 2^18 fixed point for order-invariant aggregation
#define AGG_INV   (1.0f / 262144.0f)

__device__ __forceinline__ float bf2f(unsigned short u) {
    union { unsigned int i; float f; } v; v.i = ((unsigned int)u) << 16; return v.f;
}
__device__ __forceinline__ unsigned short f2bf(float f) {
    union { float f; unsigned int i; } v; v.f = f;
    unsigned int u = v.i;
    u += 0x7FFFu + ((u >> 16) & 1u);   // round-to-nearest-even
    return (unsigned short)(u >> 16);
}

// ---------- dtype detection: int64 edge_index has odd 32-bit words == 0 ----------
__global__ void k_detect(const uint32_t* __restrict__ ei, int* __restrict__ flag) {
    if (blockIdx.x == 0 && threadIdx.x == 0) {
        uint32_t o = 0;
        #pragma unroll
        for (int i = 1; i < 16; i += 2) o |= ei[i];
        *flag = (o == 0) ? 1 : 0;
    }
}

__device__ __forceinline__ int edge_at(const void* ei, long long idx, int is64) {
    if (is64) return (int)((const long long*)ei)[idx];
    return ((const int*)ei)[idx];
}

// ---------- FUSED: gemm1 tile (blocks < g1b) + packed-degree histogram ----------
// The atomic drain leaves VALU ~99% idle (r12 PMC); the GEMM hides under it.
// h1lin is UNSCALED here; k_scale folds dis in afterwards.
__global__ __launch_bounds__(256) void k_deg_gemm1(const float* __restrict__ x, const float* __restrict__ W1,
                                                   unsigned short* __restrict__ h1lin,
                                                   const void* __restrict__ ei, const float* __restrict__ w,
                                                   unsigned int* __restrict__ packed,
                                                   unsigned char* __restrict__ rank,
                                                   const int* __restrict__ flag, int E, int N, int g1b) {
    if (blockIdx.x < g1b) {
        __shared__ float Wt[FIN * 65];      // Wt[k*65+j] = W1[j*128+k], conflict-free
        __shared__ float xt[32 * FIN];      // 16 KB
        int t = threadIdx.x;
        for (int i = t; i < FHID * FIN; i += 256) {
            int j = i >> 7, k = i & 127;
            Wt[k * 65 + j] = W1[i];
        }
        int r0 = blockIdx.x * 32;
        const float4* xg = (const float4*)(x + (size_t)r0 * FIN);
        float4* xt4 = (float4*)xt;
        #pragma unroll
        for (int q = 0; q < 4; ++q) {
            int i = t + q * 256;
            if (r0 + (i >> 5) < N) xt4[i] = xg[i];
        }
        __syncthreads();
        int j = t & 63, rg = t >> 6;
        float acc[8];
        #pragma unroll
        for (int r = 0; r < 8; ++r) acc[r] = 0.f;
        for (int kk = 0; kk < FIN; kk += 4) {
            float w0 = Wt[(kk + 0) * 65 + j];
            float w1 = Wt[(kk + 1) * 65 + j];
            float w2 = Wt[(kk + 2) * 65 + j];
            float w3 = Wt[(kk + 3) * 65 + j];
            #pragma unroll
            for (int r = 0; r < 8; ++r) {
                float4 xv = xt4[(rg * 8 + r) * 32 + (kk >> 2)];
                acc[r] += xv.x * w0 + xv.y * w1 + xv.z * w2 + xv.w * w3;
            }
        }
        #pragma unroll
        for (int r = 0; r < 8; ++r) {
            int row = r0 + rg * 8 + r;
            if (row < N) h1lin[(size_t)row * FHID + j] = f2bf(acc[r]);
        }
    }
    // ---- edge histogram part (all blocks) ----
    int e = blockIdx.x * 256 + threadIdx.x;
    if (e >= E) return;
    int is64 = *flag;
    int c = edge_at(ei, (long long)E + e, is64);
    unsigned int inc = (1u << 24) | __float2uint_rn(w[e] * FIX_SCALE);
    unsigned int old = atomicAdd(&packed[c], inc);
    rank[e] = (unsigned char)(old >> 24);
}

// ---------- packed -> deg^-1/2 ----------
__global__ __launch_bounds__(256) void k_dis(const unsigned int* __restrict__ packed,
                                             float* __restrict__ dis, int N) {
    int i = blockIdx.x * 256 + threadIdx.x;
    if (i < N) {
        float d = (float)(packed[i] & 0xFFFFFFu) * FIX_INV;
        dis[i] = (d > 0.f) ? rsqrtf(d) : 0.f;
    }
}

// ---------- t1 = dis[row] * h1lin (in place, deterministic) ----------
__global__ __launch_bounds__(256) void k_scale(unsigned int* __restrict__ t,
                                               const float* __restrict__ dis, int total) {
    int i = blockIdx.x * 256 + threadIdx.x;
    if (i >= total) return;
    float d = dis[i >> 5];                  // 32 consecutive lanes share one node
    unsigned v = t[i];
    t[i] = (unsigned)f2bf(bf2f((unsigned short)v) * d)
         | ((unsigned)f2bf(bf2f((unsigned short)(v >> 16)) * d) << 16);
}

// ---------- exclusive scan of packed counts -> row_start ----------
__global__ __launch_bounds__(256) void k_scan_part(const unsigned int* __restrict__ packed,
                                                   int* __restrict__ partial, int N) {
    __shared__ int sdata[256];
    int b = blockIdx.x, t = threadIdx.x;
    int base = b * CHUNK;
    int sum = 0;
    #pragma unroll
    for (int q = 0; q < CHUNK / 256; ++q) {
        int idx = base + q * 256 + t;
        if (idx < N) sum += (int)(packed[idx] >> 24);
    }
    sdata[t] = sum; __syncthreads();
    for (int off = 128; off > 0; off >>= 1) {
        if (t < off) sdata[t] += sdata[t + off];
        __syncthreads();
    }
    if (t == 0) partial[b] = sdata[0];
}

__global__ void k_scan_top(int* partial, int nparts, int* row_start, int N) {
    if (blockIdx.x == 0 && threadIdx.x == 0) {
        int run = 0;
        for (int i = 0; i < nparts; ++i) { int v = partial[i]; partial[i] = run; run += v; }
        row_start[N] = run;   // == E
    }
}

__global__ __launch_bounds__(256) void k_scan_chunk(const unsigned int* __restrict__ packed,
                                                    const int* __restrict__ partial,
                                                    int* __restrict__ row_start, int N) {
    __shared__ int tsum[256];
    __shared__ int toff[256];
    int b = blockIdx.x, t = threadIdx.x;
    int base = b * CHUNK + t * 8;
    int v[8]; int s = 0;
    #pragma unroll
    for (int q = 0; q < 8; ++q) {
        int idx = base + q;
        v[q] = (idx < N) ? (int)(packed[idx] >> 24) : 0;
        s += v[q];
    }
    tsum[t] = s; __syncthreads();
    if (t == 0) {
        int run = partial[b];
        for (int i = 0; i < 256; ++i) { int x = tsum[i]; toff[i] = run; run += x; }
    }
    __syncthreads();
    int ex = toff[t];
    #pragma unroll
    for (int q = 0; q < 8; ++q) {
        int idx = base + q;
        if (idx < N) row_start[idx] = ex;
        ex += v[q];
    }
}

// ---------- CSR fill (atomic-free, no dis gathers): csr = {src, w} ----------
__global__ __launch_bounds__(256) void k_fill(const void* __restrict__ ei, const float* __restrict__ w,
                                              const int* __restrict__ row_start,
                                              const unsigned char* __restrict__ rank,
                                              int2* __restrict__ csr,
                                              const int* __restrict__ flag, int E) {
    int e = blockIdx.x * 256 + threadIdx.x;
    if (e >= E) return;
    int is64 = *flag;
    int r = edge_at(ei, e, is64);
    int c = edge_at(ei, (long long)E + e, is64);
    int pos = row_start[c] + (int)rank[e];
    csr[pos] = make_int2(r, __float_as_int(w[e]));
}

// ---------- dual-node interleaved pair-gather aggregation (int-fx, order-invariant) ----------
// acc = sum w * tab[src]; caller multiplies by dis[node] (factored-out dis[c]).
// OUT_MODE 0 (agg1): t2 = dis*relu(dis*acc + b1);  OUT_MODE 1 (agg2): aggv = dis*acc
template <int OUT_MODE>
__device__ __forceinline__ void agg_fx_dual(const int2* __restrict__ csr, const int* __restrict__ row_start,
                                            const unsigned int* __restrict__ tab32,
                                            const float* __restrict__ b1, const float* __restrict__ dis,
                                            unsigned int* __restrict__ out32, int N) {
    int wid = threadIdx.x >> 6, lane = threadIdx.x & 63;
    int nodeA = blockIdx.x * 8 + wid * 2;
    if (nodeA >= N) return;
    int nodeB = nodeA + 1;
    bool hasB = nodeB < N;
    int half = lane >> 5, lpos = lane & 31;
    int baseA = row_start[nodeA], eA = row_start[nodeA + 1];
    int baseB = hasB ? eA : 0, eB = hasB ? row_start[nodeB + 1] : 0;
    int aAx0 = 0, aAy0 = 0, aAx1 = 0, aAy1 = 0;
    int aBx0 = 0, aBy0 = 0, aBx1 = 0, aBy1 = 0;
    while (baseA < eA || baseB < eB) {
        int mA = eA - baseA; mA = mA < 0 ? 0 : (mA > 64 ? 64 : mA);
        int mB = eB - baseB; mB = mB < 0 ? 0 : (mB > 64 ? 64 : mB);
        int2 entA = (lane < mA) ? csr[baseA + lane] : make_int2(0, 0);
        int2 entB = (lane < mB) ? csr[baseB + lane] : make_int2(0, 0);
        int mMax = mA > mB ? mA : mB;
        int i = 0;
        for (; i + 4 <= mMax; i += 4) {
            if (i < mA) {
                int s0 = __shfl(entA.x, i + half);     float n0 = __shfl(__int_as_float(entA.y), i + half);
                int s1 = __shfl(entA.x, i + 2 + half); float n1 = __shfl(__int_as_float(entA.y), i + 2 + half);
                unsigned v0 = tab32[(size_t)((unsigned)s0 << 5) + lpos];
                unsigned v1 = tab32[(size_t)((unsigned)s1 << 5) + lpos];
                float f0 = n0 * AGG_SC, f1 = n1 * AGG_SC;
                aAx0 += __float2int_rz(f0 * bf2f((unsigned short)v0));
                aAy0 += __float2int_rz(f0 * bf2f((unsigned short)(v0 >> 16)));
                aAx1 += __float2int_rz(f1 * bf2f((unsigned short)v1));
                aAy1 += __float2int_rz(f1 * bf2f((unsigned short)(v1 >> 16)));
            }
            if (i < mB) {
                int s0 = __shfl(entB.x, i + half);     float n0 = __shfl(__int_as_float(entB.y), i + half);
                int s1 = __shfl(entB.x, i + 2 + half); float n1 = __shfl(__int_as_float(entB.y), i + 2 + half);
                unsigned v0 = tab32[(size_t)((unsigned)s0 << 5) + lpos];
                unsigned v1 = tab32[(size_t)((unsigned)s1 << 5) + lpos];
                float f0 = n0 * AGG_SC, f1 = n1 * AGG_SC;
                aBx0 += __float2int_rz(f0 * bf2f((unsigned short)v0));
                aBy0 += __float2int_rz(f0 * bf2f((unsigned short)(v0 >> 16)));
                aBx1 += __float2int_rz(f1 * bf2f((unsigned short)v1));
                aBy1 += __float2int_rz(f1 * bf2f((unsigned short)(v1 >> 16)));
            }
        }
        for (; i < mMax; ++i) {
            if (i < mA) {
                int s0 = __shfl(entA.x, i); float n0 = __shfl(__int_as_float(entA.y), i);
                if (half) n0 = 0.f;
                unsigned v0 = tab32[(size_t)((unsigned)s0 << 5) + lpos];
                float f0 = n0 * AGG_SC;
                aAx0 += __float2int_rz(f0 * bf2f((unsigned short)v0));
                aAy0 += __float2int_rz(f0 * bf2f((unsigned short)(v0 >> 16)));
            }
            if (i < mB) {
                int s0 = __shfl(entB.x, i); float n0 = __shfl(__int_as_float(entB.y), i);
                if (half) n0 = 0.f;
                unsigned v0 = tab32[(size_t)((unsigned)s0 << 5) + lpos];
                float f0 = n0 * AGG_SC;
                aBx0 += __float2int_rz(f0 * bf2f((unsigned short)v0));
                aBy0 += __float2int_rz(f0 * bf2f((unsigned short)(v0 >> 16)));
            }
        }
        baseA += 64; baseB += 64;
    }
    int axA = aAx0 + aAx1, ayA = aAy0 + aAy1;
    axA += __shfl_xor(axA, 32); ayA += __shfl_xor(ayA, 32);   // int: order-invariant
    int axB = aBx0 + aBx1, ayB = aBy0 + aBy1;
    axB += __shfl_xor(axB, 32); ayB += __shfl_xor(ayB, 32);
    if (lane < 32) {
        float dA = dis[nodeA];
        float dB = hasB ? dis[nodeB] : 0.f;
        float fxA = (float)axA * AGG_INV * dA, fyA = (float)ayA * AGG_INV * dA;
        float fxB = (float)axB * AGG_INV * dB, fyB = (float)ayB * AGG_INV * dB;
        if (OUT_MODE == 0) {
            float2 bp = ((const float2*)b1)[lane];
            fxA = dA * fmaxf(fxA + bp.x, 0.f); fyA = dA * fmaxf(fyA + bp.y, 0.f);
            fxB = dB * fmaxf(fxB + bp.x, 0.f); fyB = dB * fmaxf(fyB + bp.y, 0.f);
        }
        out32[(size_t)nodeA * 32 + lane] = (unsigned)f2bf(fxA) | ((unsigned)f2bf(fyA) << 16);
        if (hasB)
            out32[(size_t)nodeB * 32 + lane] = (unsigned)f2bf(fxB) | ((unsigned)f2bf(fyB) << 16);
    }
}

__global__ __launch_bounds__(256) void k_agg1(const int2* __restrict__ csr, const int* __restrict__ row_start,
                                              const unsigned int* __restrict__ t1,
                                              const float* __restrict__ b1, const float* __restrict__ dis,
                                              unsigned int* __restrict__ t2, int N) {
    agg_fx_dual<0>(csr, row_start, t1, b1, dis, t2, N);
}

__global__ __launch_bounds__(256) void k_agg2(const int2* __restrict__ csr, const int* __restrict__ row_start,
                                              const unsigned int* __restrict__ t2,
                                              const float* __restrict__ dis,
                                              unsigned int* __restrict__ aggv32, int N) {
    agg_fx_dual<1>(csr, row_start, t2, (const float*)nullptr, dis, aggv32, N);
}

// ---------- GEMM2: out[N,128] = relu(aggv[N,64](bf16) @ W2[128,64]^T + b2) ----------
#define G2_ROWS 16
__global__ __launch_bounds__(256, 4) void k_gemm2(const unsigned int* __restrict__ aggv32,
                                                  const float* __restrict__ W2,
                                                  const float* __restrict__ b2,
                                                  float* __restrict__ out, int N) {
    __shared__ float Wt[FHID * 129];            // Wt[k*129+j] = W2[j*64+k]; conflict-free
    __shared__ unsigned int at[G2_ROWS * 33];
    int t = threadIdx.x;
    for (int i = t; i < FIN * FHID; i += 256) {
        int j = i >> 6, k = i & 63;
        Wt[k * 129 + j] = W2[i];
    }
    int r0 = blockIdx.x * G2_ROWS;
    for (int i = t; i < G2_ROWS * 32; i += 256) {
        int r = i >> 5, c = i & 31;
        at[r * 33 + c] = (r0 + r < N) ? aggv32[(size_t)(r0 + r) * 32 + c] : 0u;
    }
    __syncthreads();
    int j = t & 127, rg = t >> 7;
    float acc[8];
    #pragma unroll
    for (int r = 0; r < 8; ++r) acc[r] = 0.f;
    for (int c = 0; c < 32; c += 2) {
        float w0 = Wt[(2 * c + 0) * 129 + j];
        float w1 = Wt[(2 * c + 1) * 129 + j];
        float w2 = Wt[(2 * c + 2) * 129 + j];
        float w3 = Wt[(2 * c + 3) * 129 + j];
        #pragma unroll
        for (int r = 0; r < 8; ++r) {
            unsigned a01 = at[(rg * 8 + r) * 33 + c];
            unsigned a23 = at[(rg * 8 + r) * 33 + c + 1];
            acc[r] += bf2f((unsigned short)a01) * w0 + bf2f((unsigned short)(a01 >> 16)) * w1
                    + bf2f((unsigned short)a23) * w2 + bf2f((unsigned short)(a23 >> 16)) * w3;
        }
    }
    float bj = b2[j];
    #pragma unroll
    for (int r = 0; r < 8; ++r) {
        int row = r0 + rg * 8 + r;
        if (row < N) out[(size_t)row * FIN + j] = fmaxf(acc[r] + bj, 0.f);
    }
}

extern "C" void kernel_launch(void* const* d_in, const int* in_sizes, int n_in,
                              void* d_out, int out_size, void* d_ws, size_t ws_size,
                              hipStream_t stream) {
    const float* x  = (const float*)d_in[0];
    const void*  ei = d_in[1];
    const float* w  = (const float*)d_in[2];
    const float* W1 = (const float*)d_in[3];
    const float* b1 = (const float*)d_in[4];
    const float* W2 = (const float*)d_in[5];
    const float* b2 = (const float*)d_in[6];
    float* out = (float*)d_out;
    int N = in_sizes[0] / FIN;
    int E = in_sizes[2];

    char* ws = (char*)d_ws;
    size_t off = 0;
    auto alloc = [&](size_t b) { size_t o = off; off = (off + b + 255) & ~255ULL; return o; };
    int*   flag      = (int*)(ws + alloc(4));
    unsigned int* packed = (unsigned int*)(ws + alloc((size_t)N * 4));
    float* dis       = (float*)(ws + alloc((size_t)N * 4));
    int*   row_start = (int*)(ws + alloc((size_t)(N + 1) * 4));
    int*   partial   = (int*)(ws + alloc(4096));
    int2*  csr       = (int2*)(ws + alloc((size_t)E * 8));
    unsigned char* rank = (unsigned char*)(ws + alloc((size_t)E));   // own slot (fused kernel writes h1lin too)
    unsigned int* t2_32   = (unsigned int*)(ws + alloc((size_t)N * FHID * 2));
    unsigned int* aggv32  = (unsigned int*)(ws + alloc((size_t)N * FHID * 2));
    unsigned int* t1_32   = (unsigned int*)(ws + alloc((size_t)N * FHID * 2));  // h1lin then t1 (scaled in place)

    hipMemsetAsync(packed, 0, (size_t)N * 4, stream);

    k_detect<<<1, 64, 0, stream>>>((const uint32_t*)ei, flag);

    int eb = (E + 255) / 256;
    int g1b = (N + 31) / 32;
    int fused_grid = eb > g1b ? eb : g1b;
    k_deg_gemm1<<<fused_grid, 256, 0, stream>>>(x, W1, (unsigned short*)t1_32, ei, w,
                                                packed, rank, flag, E, N, g1b);
    k_dis<<<(N + 255) / 256, 256, 0, stream>>>(packed, dis, N);
    k_scale<<<(N * 32 + 255) / 256, 256, 0, stream>>>(t1_32, dis, N * 32);

    int nparts = (N + CHUNK - 1) / CHUNK;
    k_scan_part<<<nparts, 256, 0, stream>>>(packed, partial, N);
    k_scan_top<<<1, 64, 0, stream>>>(partial, nparts, row_start, N);
    k_scan_chunk<<<nparts, 256, 0, stream>>>(packed, partial, row_start, N);

    k_fill<<<eb, 256, 0, stream>>>(ei, w, row_start, rank, csr, flag, E);

    k_agg1<<<(N + 7) / 8, 256, 0, stream>>>(csr, row_start, t1_32, b1, dis, t2_32, N);
    k_agg2<<<(N + 7) / 8, 256, 0, stream>>>(csr, row_start, t2_32, dis, aggv32, N);
    k_gemm2<<<(N + G2_ROWS - 1) / G2_ROWS, 256, 0, stream>>>(aggv32, W2, b2, out, N);
}